// Round 18
// baseline (212.036 us; speedup 1.0000x reference)
//
#include <hip/hip_runtime.h>
#include <hip/hip_bf16.h>

#define IN_NODE 64
#define IN_EDGE 16
#define HID 64
#define BKT_SHIFT 8    // 256 dst-nodes per bucket
#define PART_T 800     // edges per partition block (E=800K -> 1000 blocks; 19KB LDS)
#define PART_TMAX 800  // LDS record capacity (>= PART_T)

using f32x4 = __attribute__((ext_vector_type(4))) float;
using f32x2 = __attribute__((ext_vector_type(2))) float;
using bf16x8 = __attribute__((ext_vector_type(8))) short;
#define MFMA16(a, b, c) __builtin_amdgcn_mfma_f32_16x16x32_bf16(a, b, c, 0, 0, 0)

__device__ __forceinline__ unsigned short f32_to_bf16u(float f) {
    __hip_bfloat16 hb = __float2bfloat16(f);
    return *(unsigned short*)&hb;
}
__device__ __forceinline__ float bf16u_to_f32(unsigned short u) {
    return __uint_as_float(((unsigned)u) << 16);
}

// ---------------------------------------------------------------- bucket-granularity CSR prologue

__global__ __launch_bounds__(256) void btot_kernel(const int* __restrict__ dst,
                                                   int* __restrict__ btot, int E, int NBK) {
    __shared__ int lhist[256];
    const int t = threadIdx.x;
    lhist[t] = 0;
    __syncthreads();
    const int stride = gridDim.x * 256;
    for (int e = blockIdx.x * 256 + t; e < E; e += stride)
        atomicAdd(&lhist[dst[e] >> BKT_SHIFT], 1);
    __syncthreads();
    if (t < NBK && lhist[t]) atomicAdd(&btot[t], lhist[t]);
}

// single block: bbase = exclusive scan of btot; seed gbcur; row_ptr[N]=E; ALSO does
// the (tiny) edge-logit q-vector prep (was prep_q_kernel) on lanes t<64.
__global__ __launch_bounds__(256) void scan_btot_kernel(
    const int* __restrict__ btot, int* __restrict__ bbase, int* __restrict__ gbcur,
    int* __restrict__ row_ptr, const float* __restrict__ We0, const float* __restrict__ ae0,
    const float* __restrict__ We1, const float* __restrict__ ae1, const float* __restrict__ We2,
    const float* __restrict__ ae2, float* __restrict__ q, int NBK, int N, int E) {
    __shared__ int sd[256];
    int t = threadIdx.x;
    int v = (t < NBK) ? btot[t] : 0;
    sd[t] = v;
    __syncthreads();
    for (int off = 1; off < 256; off <<= 1) {
        int tmp = (t >= off) ? sd[t - off] : 0;
        __syncthreads();
        sd[t] += tmp;
        __syncthreads();
    }
    int excl = sd[t] - v;
    if (t < NBK) {
        bbase[t] = excl;
        gbcur[t] = excl;
    }
    if (t == NBK - 1) bbase[NBK] = sd[t];
    if (t == 0) row_ptr[N] = E;
    // q prep (no barriers below — divergence safe)
    if (t < 32) {
        int k = t >> 1, hh = t & 1;
        float s = 0.f;
        for (int c = 0; c < HID; ++c) s += We0[k * 128 + hh * 64 + c] * ae0[hh * 64 + c];
        q[k * 4 + hh] = s;
    } else if (t < 48) {
        int k = t - 32;
        float s = 0.f;
        for (int c = 0; c < HID; ++c) s += We1[k * 64 + c] * ae1[c];
        q[k * 4 + 2] = s;
    } else if (t < 64) {
        int k = t - 48;
        float s = 0.f;
        for (int c = 0; c < HID; ++c) s += We2[k * 64 + c] * ae2[c];
        q[k * 4 + 3] = s;
    }
}

// ---------------------------------------------------------------- LDS-staged radix partition
// FUSED: edge-logit compute + e-passthrough copy. R17 lesson: the streaming phases
// need occupancy — 19KB LDS/block (PART_T=800, 1000 blocks) gives ~4 blocks/CU so the
// copy phase can approach HBM BW instead of idling at 2 blocks/CU.

__global__ __launch_bounds__(256) void partition_kernel(
    const int* __restrict__ dst, const int* __restrict__ src, const float* __restrict__ w,
    const float* __restrict__ q, int* __restrict__ gbcur, unsigned* __restrict__ part_sd,
    float4* __restrict__ part_ae4, const float4* __restrict__ e4, float4* __restrict__ out_e4,
    int E, int NBK) {
    __shared__ int lhist[256];   // counts -> cursor
    __shared__ int ldelta[256];  // global_base - lds_base per bucket
    __shared__ float qs[64];
    __shared__ unsigned s_sd[PART_TMAX];
    __shared__ float4 s_ae4[PART_TMAX];
    __shared__ unsigned char s_bkt[PART_TMAX];
    const int t = threadIdx.x;
    const int e0 = blockIdx.x * PART_T;
    const int e1 = min(e0 + PART_T, E);
    const int cnt_total = e1 - e0;
    if (t < 64) qs[t] = q[t];
    lhist[t] = 0;
    __syncthreads();
    // phase 1: histogram (4x unrolled over the 800-edge tile)
    {
        int e = e0 + t;
        int b0v = (e < e1) ? (dst[e] >> BKT_SHIFT) : -1;
        int e2 = e + 256;
        int b1v = (e2 < e1) ? (dst[e2] >> BKT_SHIFT) : -1;
        int e3 = e2 + 256;
        int b2v = (e3 < e1) ? (dst[e3] >> BKT_SHIFT) : -1;
        int e4i = e3 + 256;
        int b3v = (e4i < e1) ? (dst[e4i] >> BKT_SHIFT) : -1;
        if (b0v >= 0) atomicAdd(&lhist[b0v], 1);
        if (b1v >= 0) atomicAdd(&lhist[b1v], 1);
        if (b2v >= 0) atomicAdd(&lhist[b2v], 1);
        if (b3v >= 0) atomicAdd(&lhist[b3v], 1);
    }
    __syncthreads();
    // phase 2: block exclusive scan of lhist -> LDS base; reserve global ranges
    int cnt = lhist[t];
    __syncthreads();
    lhist[t] = cnt;
    __syncthreads();
    for (int off = 1; off < 256; off <<= 1) {
        int tmp = (t >= off) ? lhist[t - off] : 0;
        __syncthreads();
        lhist[t] += tmp;
        __syncthreads();
    }
    int lbase = lhist[t] - cnt;  // exclusive
    int gbase = (t < NBK && cnt) ? atomicAdd(&gbcur[t], cnt) : 0;
    ldelta[t] = gbase - lbase;
    __syncthreads();
    lhist[t] = lbase;  // becomes the LDS cursor
    __syncthreads();
    // phase 3: compute logits + write records into LDS, bucket-grouped (4x unrolled)
    for (int eb = e0 + t; eb < e1; eb += 1024) {
        int d4[4], s4[4];
        bool v4[4];
        float4 a4[4];
#pragma unroll
        for (int j = 0; j < 4; ++j) {
            int e = eb + j * 256;
            v4[j] = e < e1;
            int ec = v4[j] ? e : e0;
            d4[j] = dst[ec];
            s4[j] = src[ec];
            const float4* w4p = (const float4*)(w + (size_t)ec * IN_EDGE);
            float a0 = 0.f, a1 = 0.f, a2 = 0.f, a3 = 0.f;
#pragma unroll
            for (int kq = 0; kq < 4; ++kq) {
                float4 wv = w4p[kq];
                float wk[4] = {wv.x, wv.y, wv.z, wv.w};
#pragma unroll
                for (int tt = 0; tt < 4; ++tt) {
                    int k = kq * 4 + tt;
                    a0 += wk[tt] * qs[k * 4 + 0];
                    a1 += wk[tt] * qs[k * 4 + 1];
                    a2 += wk[tt] * qs[k * 4 + 2];
                    a3 += wk[tt] * qs[k * 4 + 3];
                }
            }
            a4[j] = make_float4(a0, a1, a2, a3);
        }
#pragma unroll
        for (int j = 0; j < 4; ++j) {
            if (v4[j]) {
                int b = d4[j] >> BKT_SHIFT;
                int slot = atomicAdd(&lhist[b], 1);
                s_sd[slot] = ((unsigned)d4[j] << 16) | (unsigned)s4[j];  // both < 65536
                s_ae4[slot] = a4[j];
                s_bkt[slot] = (unsigned char)b;
            }
        }
    }
    __syncthreads();
    // phase 4: coalesced flush LDS -> global (bucket-grouped order)
    for (int r = t; r < cnt_total; r += 256) {
        int b = s_bkt[r];
        int g = ldelta[b] + r;
        part_sd[g] = s_sd[r];
        part_ae4[g] = s_ae4[r];
    }
    // phase 5: e passthrough for this block's edge range (pure streaming)
    const int q0 = e0 * 4, q1 = e1 * 4;  // float4 index range ([E,16] f32 = 4 f4/edge)
    for (int i = q0 + t; i < q1; i += 256) out_e4[i] = e4[i];
}

// ---------------------------------------------------------------- bucket scatter + per-node CSR

__global__ __launch_bounds__(256) void bucket_scatter_kernel(
    const unsigned* __restrict__ part_sd, const float4* __restrict__ part_ae4,
    const int* __restrict__ bbase, int* __restrict__ row_ptr, unsigned short* __restrict__ csr_src,
    float2* __restrict__ ae01, float* __restrict__ ae2, float* __restrict__ ae3, int N) {
    __shared__ int cnt[256];  // per-node counts -> scan -> cursors
    const int t = threadIdx.x;
    const int node0 = blockIdx.x << BKT_SHIFT;
    const int nend = min(node0 + 256, N);
    const int p0 = bbase[blockIdx.x];
    const int p1 = bbase[blockIdx.x + 1];
    cnt[t] = 0;
    __syncthreads();
    // pass 1: per-node histogram (4x unrolled)
    for (int pb = p0 + t; pb < p1; pb += 1024) {
        int d4[4];
        bool v4[4];
#pragma unroll
        for (int j = 0; j < 4; ++j) {
            int pp = pb + j * 256;
            v4[j] = pp < p1;
            d4[j] = (int)(part_sd[v4[j] ? pp : p0] >> 16);
        }
#pragma unroll
        for (int j = 0; j < 4; ++j)
            if (v4[j]) atomicAdd(&cnt[d4[j] - node0], 1);
    }
    __syncthreads();
    // scan -> row_ptr + cursors
    int c = cnt[t];
    __syncthreads();
    cnt[t] = c;
    __syncthreads();
    for (int off = 1; off < 256; off <<= 1) {
        int tmp = (t >= off) ? cnt[t - off] : 0;
        __syncthreads();
        cnt[t] += tmp;
        __syncthreads();
    }
    int excl = cnt[t] - c;
    if (node0 + t < nend) row_ptr[node0 + t] = p0 + excl;
    __syncthreads();
    cnt[t] = p0 + excl;  // cursor
    __syncthreads();
    // pass 2: scatter records (4x unrolled)
    for (int pb = p0 + t; pb < p1; pb += 1024) {
        unsigned sd4[4];
        float4 a4[4];
        bool v4[4];
#pragma unroll
        for (int j = 0; j < 4; ++j) {
            int pp = pb + j * 256;
            v4[j] = pp < p1;
            int pc = v4[j] ? pp : p0;
            sd4[j] = part_sd[pc];  // coalesced, L2-hot
            a4[j] = part_ae4[pc];  // coalesced
        }
#pragma unroll
        for (int j = 0; j < 4; ++j) {
            if (v4[j]) {
                int d = (int)(sd4[j] >> 16);
                int slot = atomicAdd(&cnt[d - node0], 1);
                csr_src[slot] = (unsigned short)(sd4[j] & 0xffffu);
                ae01[slot] = make_float2(a4[j].x, a4[j].y);
                ae2[slot] = a4[j].z;
                ae3[slot] = a4[j].w;
            }
        }
    }
}

// ---------------------------------------------------------------- MFMA node GEMM + alpha
// A-frag: row = lane&15, k = 32*kt + 8*(lane>>4) + j.  B-frag: col = lane&15, same k.
// C/D (m89-verified): col = lane&15, row = (lane>>4)*4 + reg.
// xwb: FP8 e4m3 message payload, PERMUTED per (node,head): col' = (c&15)*4 + (c>>4).

__device__ __forceinline__ bf16x8 bfrag_w(const float* __restrict__ W, int ldc, int k0, int c) {
    bf16x8 f;
#pragma unroll
    for (int j = 0; j < 8; ++j) f[j] = (short)f32_to_bf16u(W[(k0 + j) * ldc + c]);
    return f;
}

__device__ __forceinline__ bf16x8 afrag_f32(const float* __restrict__ row, int k0) {
    float4 u = *(const float4*)(row + k0);
    float4 v = *(const float4*)(row + k0 + 4);
    bf16x8 f;
    f[0] = (short)f32_to_bf16u(u.x);
    f[1] = (short)f32_to_bf16u(u.y);
    f[2] = (short)f32_to_bf16u(u.z);
    f[3] = (short)f32_to_bf16u(u.w);
    f[4] = (short)f32_to_bf16u(v.x);
    f[5] = (short)f32_to_bf16u(v.y);
    f[6] = (short)f32_to_bf16u(v.z);
    f[7] = (short)f32_to_bf16u(v.w);
    return f;
}

template <int H, bool ABF16>
__global__ __launch_bounds__(256) void xw_alpha_mfma_kernel(
    const float* __restrict__ xf, const unsigned short* __restrict__ xb,
    const float* __restrict__ W, const float* __restrict__ a_src, const float* __restrict__ a_dst,
    unsigned char* __restrict__ xwb, float* __restrict__ alpha_src,
    float* __restrict__ alpha_dst, int ntiles) {
    const int lane = threadIdx.x & 63;
    const int wv = threadIdx.x >> 6;
    const int tile = blockIdx.x * 4 + wv;
    if (tile >= ntiles) return;
    const int cl = lane & 15, kg = lane >> 4;
    const int n0 = tile * 16;

    bf16x8 bf[2][4 * H];
    float asr[4 * H], adr[4 * H];
#pragma unroll
    for (int kt = 0; kt < 2; ++kt)
#pragma unroll
        for (int ct = 0; ct < 4 * H; ++ct)
            bf[kt][ct] = bfrag_w(W, 64 * H, kt * 32 + kg * 8, ct * 16 + cl);
#pragma unroll
    for (int ct = 0; ct < 4 * H; ++ct) {
        int hh = ct >> 2;
        int c = (ct & 3) * 16 + cl;
        asr[ct] = a_src[hh * 64 + c];
        adr[ct] = a_dst[hh * 64 + c];
    }

    bf16x8 af0, af1;
    if (ABF16) {
        const unsigned short* rp = xb + (size_t)(n0 + cl) * 64;
        af0 = *(const bf16x8*)(rp + kg * 8);
        af1 = *(const bf16x8*)(rp + 32 + kg * 8);
    } else {
        const float* rp = xf + (size_t)(n0 + cl) * 64;
        af0 = afrag_f32(rp, kg * 8);
        af1 = afrag_f32(rp, 32 + kg * 8);
    }

    f32x4 acc[4 * H];
#pragma unroll
    for (int ct = 0; ct < 4 * H; ++ct) {
        f32x4 z = {0.f, 0.f, 0.f, 0.f};
        z = MFMA16(af0, bf[0][ct], z);
        acc[ct] = MFMA16(af1, bf[1][ct], z);
    }

    // store xwb (fp8, permuted layout): node r, head hh: uint (4 fp8) at col' = cl*4
#pragma unroll
    for (int r = 0; r < 4; ++r) {
        int n = n0 + kg * 4 + r;
#pragma unroll
        for (int hh = 0; hh < H; ++hh) {
            int pk = 0;
            pk = __builtin_amdgcn_cvt_pk_fp8_f32(acc[hh * 4 + 0][r], acc[hh * 4 + 1][r], pk,
                                                 false);
            pk = __builtin_amdgcn_cvt_pk_fp8_f32(acc[hh * 4 + 2][r], acc[hh * 4 + 3][r], pk,
                                                 true);
            *(unsigned*)(xwb + ((size_t)n * H + hh) * 64 + cl * 4) = (unsigned)pk;
        }
    }

    // alpha logits: dot over the 64 cols of head hh, reduced across the 16-lane group
#pragma unroll
    for (int hh = 0; hh < H; ++hh) {
#pragma unroll
        for (int r = 0; r < 4; ++r) {
            float vs = 0.f, vd = 0.f;
#pragma unroll
            for (int q = 0; q < 4; ++q) {
                vs += acc[hh * 4 + q][r] * asr[hh * 4 + q];
                vd += acc[hh * 4 + q][r] * adr[hh * 4 + q];
            }
#pragma unroll
            for (int off = 8; off; off >>= 1) {
                vs += __shfl_xor(vs, off, 16);
                vd += __shfl_xor(vd, off, 16);
            }
            if (cl == r) {
                int n = n0 + kg * 4 + r;
                alpha_src[n * H + hh] = vs;
                alpha_dst[n * H + hh] = vd;
            }
        }
    }
}

// readout: out[n][c] = sum_k x[n][k]*Wr[k][c] + br[c], fp32 out
__global__ __launch_bounds__(256) void readout_mfma_kernel(const unsigned short* __restrict__ xb,
                                                           const float* __restrict__ Wr,
                                                           const float* __restrict__ br,
                                                           float* __restrict__ out, int ntiles) {
    const int lane = threadIdx.x & 63;
    const int wv = threadIdx.x >> 6;
    const int tile = blockIdx.x * 4 + wv;
    if (tile >= ntiles) return;
    const int cl = lane & 15, kg = lane >> 4;
    const int n0 = tile * 16;

    bf16x8 bf[2][4];
    float brv[4];
#pragma unroll
    for (int kt = 0; kt < 2; ++kt)
#pragma unroll
        for (int ct = 0; ct < 4; ++ct) bf[kt][ct] = bfrag_w(Wr, 64, kt * 32 + kg * 8, ct * 16 + cl);
#pragma unroll
    for (int ct = 0; ct < 4; ++ct) brv[ct] = br[ct * 16 + cl];

    const unsigned short* rp = xb + (size_t)(n0 + cl) * 64;
    bf16x8 af0 = *(const bf16x8*)(rp + kg * 8);
    bf16x8 af1 = *(const bf16x8*)(rp + 32 + kg * 8);

    f32x4 acc[4];
#pragma unroll
    for (int ct = 0; ct < 4; ++ct) {
        f32x4 z = {0.f, 0.f, 0.f, 0.f};
        z = MFMA16(af0, bf[0][ct], z);
        acc[ct] = MFMA16(af1, bf[1][ct], z);
    }
#pragma unroll
    for (int r = 0; r < 4; ++r) {
        int n = n0 + kg * 4 + r;
#pragma unroll
        for (int ct = 0; ct < 4; ++ct) out[(size_t)n * 64 + ct * 16 + cl] = acc[ct][r] + brv[ct];
    }
}

// ---------------------------------------------------------------- aggregation
// 16-lane-group-per-node, fp8 payload (uint per lane = 4 fp8), SoA ae planes.

template <int H, int AEOFF>
__global__ __launch_bounds__(256) void aggregate16_kernel(
    const unsigned char* __restrict__ xwb, const float* __restrict__ alpha_src,
    const float* __restrict__ alpha_dst, const void* __restrict__ aeplane,
    const int* __restrict__ row_ptr, const unsigned short* __restrict__ csr_src,
    const float* __restrict__ bias, unsigned short* __restrict__ x_out, int N) {
    const int l = threadIdx.x & 15;    // sublane within group
    const int grp = threadIdx.x >> 4;  // group within block: 0..15
    const int n = blockIdx.x * 16 + grp;
    if (n >= N) return;
    const int base = row_ptr[n];
    const int deg = row_ptr[n + 1] - base;

    float bb[4];
#pragma unroll
    for (int q = 0; q < 4; ++q) bb[q] = bias[q * 16 + l];

    float m[H], den[H], o[H][4], ad[H];
#pragma unroll
    for (int h = 0; h < H; ++h) {
        m[h] = -1e30f;
        den[h] = 0.f;
        o[h][0] = o[h][1] = o[h][2] = o[h][3] = 0.f;
        ad[h] = alpha_dst[n * H + h];
    }

    for (int start = 0; start < deg; start += 16) {
        int j = start + l;
        bool act = j < deg;
        int s = 0;
        float a[H], ev[H];
        if (act) {
            s = csr_src[base + j];
            float asv[H], aev[H];
            if (H == 2) {
                float2 ae = ((const float2*)aeplane)[base + j];
                aev[0] = ae.x;
                aev[H - 1] = ae.y;
                float2 as2 = *((const float2*)alpha_src + s);
                asv[0] = as2.x;
                asv[H - 1] = as2.y;
            } else {
                aev[0] = ((const float*)aeplane)[base + j];
                asv[0] = alpha_src[s];
            }
#pragma unroll
            for (int h = 0; h < H; ++h) {
                float av = asv[h] + ad[h] + aev[h];
                a[h] = (av > 0.f) ? av : 0.2f * av;
            }
        } else {
#pragma unroll
            for (int h = 0; h < H; ++h) a[h] = -1e30f;
        }
        int cnt = min(deg - start, 16);
#pragma unroll
        for (int h = 0; h < H; ++h) {
            float cm = a[h];
#pragma unroll
            for (int off = 8; off; off >>= 1) cm = fmaxf(cm, __shfl_xor(cm, off, 16));
            float m_new = fmaxf(m[h], cm);
            float scale = __expf(m[h] - m_new);
            ev[h] = act ? __expf(a[h] - m_new) : 0.f;
            float cs = ev[h];
#pragma unroll
            for (int off = 8; off; off >>= 1) cs += __shfl_xor(cs, off, 16);
            den[h] = den[h] * scale + cs;
#pragma unroll
            for (int q = 0; q < 4; ++q) o[h][q] *= scale;
            m[h] = m_new;
        }
#pragma unroll 8
        for (int jj = 0; jj < cnt; ++jj) {
            int sj = __shfl(s, jj, 16);
#pragma unroll
            for (int h = 0; h < H; ++h) {
                float ej = __shfl(ev[h], jj, 16);
                unsigned v = *((const unsigned*)(xwb + ((size_t)sj * H + h) * 64) + l);
                f32x2 lo = __builtin_amdgcn_cvt_pk_f32_fp8((int)v, false);
                f32x2 hi = __builtin_amdgcn_cvt_pk_f32_fp8((int)v, true);
                o[h][0] += ej * lo[0];
                o[h][1] += ej * lo[1];
                o[h][2] += ej * hi[0];
                o[h][3] += ej * hi[1];
            }
        }
    }

#pragma unroll
    for (int q = 0; q < 4; ++q) {
        float acc = 0.f;
#pragma unroll
        for (int h = 0; h < H; ++h) acc += o[h][q] / (den[h] + 1e-16f);
        float r = acc * (H == 2 ? 0.5f : 1.f) + bb[q];
        r = r / (1.f + __expf(-r));  // silu
        x_out[(size_t)n * 64 + q * 16 + l] = f32_to_bf16u(r);  // un-permute: col = q*16+l
    }
}

// ---------------------------------------------------------------- launcher

static inline char* carve(char*& p, size_t bytes) {
    char* r = p;
    p += (bytes + 255) & ~(size_t)255;
    return r;
}

extern "C" void kernel_launch(void* const* d_in, const int* in_sizes, int n_in, void* d_out,
                              int out_size, void* d_ws, size_t ws_size, hipStream_t stream) {
    const int N = in_sizes[0] / IN_NODE;
    const int E = in_sizes[1] / IN_EDGE;

    const float* h = (const float*)d_in[0];
    const float* e = (const float*)d_in[1];
    const int* edge_index = (const int*)d_in[2];
    const float* w = (const float*)d_in[3];
    const float* W0 = (const float*)d_in[4];
    const float* as0 = (const float*)d_in[5];
    const float* ad0 = (const float*)d_in[6];
    const float* We0 = (const float*)d_in[7];
    const float* ae0 = (const float*)d_in[8];
    const float* b0 = (const float*)d_in[9];
    const float* W1 = (const float*)d_in[10];
    const float* as1 = (const float*)d_in[11];
    const float* ad1 = (const float*)d_in[12];
    const float* We1 = (const float*)d_in[13];
    const float* ae1 = (const float*)d_in[14];
    const float* b1 = (const float*)d_in[15];
    const float* W2 = (const float*)d_in[16];
    const float* as2 = (const float*)d_in[17];
    const float* ad2 = (const float*)d_in[18];
    const float* We2 = (const float*)d_in[19];
    const float* ae2 = (const float*)d_in[20];
    const float* b2 = (const float*)d_in[21];
    const float* Wr = (const float*)d_in[22];
    const float* br = (const float*)d_in[23];

    const int* src = edge_index;
    const int* dst = edge_index + E;

    float* out_x = (float*)d_out;                        // [N,64]
    float* out_e = (float*)d_out + (size_t)N * IN_NODE;  // [E,16] passthrough

    char* p = (char*)d_ws;
    unsigned char* xwb = (unsigned char*)carve(p, (size_t)N * 128);      // fp8 [N,H,64] perm
    unsigned short* xA = (unsigned short*)carve(p, (size_t)N * 64 * 2);  // bf16 [N,64]
    unsigned short* xB = (unsigned short*)carve(p, (size_t)N * 64 * 2);  // bf16 [N,64]
    float* csr_ae01 = (float*)carve(p, (size_t)E * 2 * 4);  // SoA logit planes
    float* csr_ae2 = (float*)carve(p, (size_t)E * 4);
    float* csr_ae3 = (float*)carve(p, (size_t)E * 4);
    float* a_src = (float*)carve(p, (size_t)N * 2 * 4);
    float* a_dst = (float*)carve(p, (size_t)N * 2 * 4);
    float* qall = (float*)carve(p, 64 * 4);
    int* row_ptr = (int*)carve(p, (size_t)(N + 1) * 4);
    int* btot = (int*)carve(p, 256 * 4);
    int* bbase = (int*)carve(p, 257 * 4);
    unsigned short* csr_src = (unsigned short*)carve(p, (size_t)E * 2);
    unsigned* part_sd = (unsigned*)carve(p, (size_t)E * 4);
    float* part_ae4 = (float*)carve(p, (size_t)E * 4 * 4);
    int* gbcur = (int*)carve(p, 1024 * 4);

    const int ngrid16 = (N + 15) / 16;
    const int NBK = (N + 255) >> BKT_SHIFT;             // dst-node buckets of 256
    const int PART_BLOCKS = (E + PART_T - 1) / PART_T;  // 1000 blocks @ PART_T=800
    const int ntiles = (N + 15) / 16;                   // 16-node MFMA tiles
    const int ggrid = (ntiles + 3) / 4;                 // 4 waves/block, 1 tile/wave

    // bucket-granularity CSR prologue (196 counters, not 50K); q-prep fused into scan
    hipMemsetAsync(btot, 0, 256 * 4, stream);
    btot_kernel<<<512, 256, 0, stream>>>(dst, btot, E, NBK);
    scan_btot_kernel<<<1, 256, 0, stream>>>(btot, bbase, gbcur, row_ptr, We0, ae0, We1, ae1, We2,
                                            ae2, qall, NBK, N, E);

    // LDS-staged partition (logits + e-passthrough fused) + bucket scatter (builds row_ptr)
    partition_kernel<<<PART_BLOCKS, 256, 0, stream>>>(dst, src, w, qall, gbcur, part_sd,
                                                      (float4*)part_ae4, (const float4*)e,
                                                      (float4*)out_e, E, NBK);
    bucket_scatter_kernel<<<NBK, 256, 0, stream>>>(part_sd, (const float4*)part_ae4, bbase,
                                                   row_ptr, csr_src, (float2*)csr_ae01, csr_ae2,
                                                   csr_ae3, N);

    // layer 0 (H=2), input h fp32
    xw_alpha_mfma_kernel<2, false><<<ggrid, 256, 0, stream>>>(h, nullptr, W0, as0, ad0, xwb, a_src,
                                                              a_dst, ntiles);
    aggregate16_kernel<2, 0><<<ngrid16, 256, 0, stream>>>(xwb, a_src, a_dst, csr_ae01, row_ptr,
                                                          csr_src, b0, xA, N);
    // layer 1 (H=1), input xA bf16
    xw_alpha_mfma_kernel<1, true><<<ggrid, 256, 0, stream>>>(nullptr, xA, W1, as1, ad1, xwb, a_src,
                                                             a_dst, ntiles);
    aggregate16_kernel<1, 2><<<ngrid16, 256, 0, stream>>>(xwb, a_src, a_dst, csr_ae2, row_ptr,
                                                          csr_src, b1, xB, N);
    // layer 2 (H=1), input xB bf16
    xw_alpha_mfma_kernel<1, true><<<ggrid, 256, 0, stream>>>(nullptr, xB, W2, as2, ad2, xwb, a_src,
                                                             a_dst, ntiles);
    aggregate16_kernel<1, 3><<<ngrid16, 256, 0, stream>>>(xwb, a_src, a_dst, csr_ae3, row_ptr,
                                                          csr_src, b2, xA, N);
    // readout, input xA bf16
    readout_mfma_kernel<<<ggrid, 256, 0, stream>>>(xA, Wr, br, out_x, ntiles);
}

// Round 19
// 200.031 us; speedup vs baseline: 1.0600x; 1.0600x over previous
//
#include <hip/hip_runtime.h>
#include <hip/hip_bf16.h>

#define IN_NODE 64
#define IN_EDGE 16
#define HID 64
#define BKT_SHIFT 8     // 256 dst-nodes per bucket
#define PART_T 1563     // edges per partition block (proven best, R13-R17)
#define PART_TMAX 1600  // LDS record capacity (>= PART_T)

using f32x4 = __attribute__((ext_vector_type(4))) float;
using f32x2 = __attribute__((ext_vector_type(2))) float;
using bf16x8 = __attribute__((ext_vector_type(8))) short;
#define MFMA16(a, b, c) __builtin_amdgcn_mfma_f32_16x16x32_bf16(a, b, c, 0, 0, 0)

__device__ __forceinline__ unsigned short f32_to_bf16u(float f) {
    __hip_bfloat16 hb = __float2bfloat16(f);
    return *(unsigned short*)&hb;
}
__device__ __forceinline__ float bf16u_to_f32(unsigned short u) {
    return __uint_as_float(((unsigned)u) << 16);
}

// ---------------------------------------------------------------- bucket-granularity CSR prologue
// btot ALSO carries the e-passthrough copy: it is a pure high-occupancy stream
// (512 blocks, 1KB LDS) so the 102MB copy runs at near-peak HBM BW here — unlike
// fused into partition (R17/R18: ~2GB/ms due to barriers + low occupancy).

__global__ __launch_bounds__(256) void btot_kernel(const int* __restrict__ dst,
                                                   int* __restrict__ btot,
                                                   const float4* __restrict__ e4,
                                                   float4* __restrict__ out_e4, int n4, int E,
                                                   int NBK) {
    __shared__ int lhist[256];
    const int t = threadIdx.x;
    lhist[t] = 0;
    __syncthreads();
    const int stride = gridDim.x * 256;
    for (int e = blockIdx.x * 256 + t; e < E; e += stride)
        atomicAdd(&lhist[dst[e] >> BKT_SHIFT], 1);
    __syncthreads();
    if (t < NBK && lhist[t]) atomicAdd(&btot[t], lhist[t]);
    // e passthrough (grid-stride, coalesced, no barriers needed)
    for (int i = blockIdx.x * 256 + t; i < n4; i += stride) out_e4[i] = e4[i];
}

// single block: bbase = exclusive scan of btot; seed gbcur; row_ptr[N]=E; ALSO does
// the (tiny) edge-logit q-vector prep on lanes t<64.
__global__ __launch_bounds__(256) void scan_btot_kernel(
    const int* __restrict__ btot, int* __restrict__ bbase, int* __restrict__ gbcur,
    int* __restrict__ row_ptr, const float* __restrict__ We0, const float* __restrict__ ae0,
    const float* __restrict__ We1, const float* __restrict__ ae1, const float* __restrict__ We2,
    const float* __restrict__ ae2, float* __restrict__ q, int NBK, int N, int E) {
    __shared__ int sd[256];
    int t = threadIdx.x;
    int v = (t < NBK) ? btot[t] : 0;
    sd[t] = v;
    __syncthreads();
    for (int off = 1; off < 256; off <<= 1) {
        int tmp = (t >= off) ? sd[t - off] : 0;
        __syncthreads();
        sd[t] += tmp;
        __syncthreads();
    }
    int excl = sd[t] - v;
    if (t < NBK) {
        bbase[t] = excl;
        gbcur[t] = excl;
    }
    if (t == NBK - 1) bbase[NBK] = sd[t];
    if (t == 0) row_ptr[N] = E;
    // q prep (no barriers below — divergence safe)
    if (t < 32) {
        int k = t >> 1, hh = t & 1;
        float s = 0.f;
        for (int c = 0; c < HID; ++c) s += We0[k * 128 + hh * 64 + c] * ae0[hh * 64 + c];
        q[k * 4 + hh] = s;
    } else if (t < 48) {
        int k = t - 32;
        float s = 0.f;
        for (int c = 0; c < HID; ++c) s += We1[k * 64 + c] * ae1[c];
        q[k * 4 + 2] = s;
    } else if (t < 64) {
        int k = t - 48;
        float s = 0.f;
        for (int c = 0; c < HID; ++c) s += We2[k * 64 + c] * ae2[c];
        q[k * 4 + 3] = s;
    }
}

// ---------------------------------------------------------------- LDS-staged radix partition
// FUSED with edge-logit compute (copy moved out to btot; R17/R18 showed the copy
// cannot reach streaming BW inside this barriered structure).

__global__ __launch_bounds__(256) void partition_kernel(
    const int* __restrict__ dst, const int* __restrict__ src, const float* __restrict__ w,
    const float* __restrict__ q, int* __restrict__ gbcur, unsigned* __restrict__ part_sd,
    float4* __restrict__ part_ae4, int E, int NBK) {
    __shared__ int lhist[256];   // counts -> cursor
    __shared__ int ldelta[256];  // global_base - lds_base per bucket
    __shared__ float qs[64];
    __shared__ unsigned s_sd[PART_TMAX];
    __shared__ float4 s_ae4[PART_TMAX];
    __shared__ unsigned char s_bkt[PART_TMAX];
    const int t = threadIdx.x;
    const int e0 = blockIdx.x * PART_T;
    const int e1 = min(e0 + PART_T, E);
    const int cnt_total = e1 - e0;
    if (t < 64) qs[t] = q[t];
    lhist[t] = 0;
    __syncthreads();
    // phase 1: histogram (4x unrolled)
    for (int eb = e0 + t; eb < e1; eb += 1024) {
        int b4[4];
        bool v4[4];
#pragma unroll
        for (int j = 0; j < 4; ++j) {
            int e = eb + j * 256;
            v4[j] = e < e1;
            b4[j] = dst[v4[j] ? e : e0] >> BKT_SHIFT;
        }
#pragma unroll
        for (int j = 0; j < 4; ++j)
            if (v4[j]) atomicAdd(&lhist[b4[j]], 1);
    }
    __syncthreads();
    // phase 2: block exclusive scan of lhist -> LDS base; reserve global ranges
    int cnt = lhist[t];
    __syncthreads();
    lhist[t] = cnt;
    __syncthreads();
    for (int off = 1; off < 256; off <<= 1) {
        int tmp = (t >= off) ? lhist[t - off] : 0;
        __syncthreads();
        lhist[t] += tmp;
        __syncthreads();
    }
    int lbase = lhist[t] - cnt;  // exclusive
    int gbase = (t < NBK && cnt) ? atomicAdd(&gbcur[t], cnt) : 0;
    ldelta[t] = gbase - lbase;
    __syncthreads();
    lhist[t] = lbase;  // becomes the LDS cursor
    __syncthreads();
    // phase 3: compute logits + write records into LDS, bucket-grouped (4x unrolled)
    for (int eb = e0 + t; eb < e1; eb += 1024) {
        int d4[4], s4[4];
        bool v4[4];
        float4 a4[4];
#pragma unroll
        for (int j = 0; j < 4; ++j) {
            int e = eb + j * 256;
            v4[j] = e < e1;
            int ec = v4[j] ? e : e0;
            d4[j] = dst[ec];
            s4[j] = src[ec];
            const float4* w4p = (const float4*)(w + (size_t)ec * IN_EDGE);
            float a0 = 0.f, a1 = 0.f, a2 = 0.f, a3 = 0.f;
#pragma unroll
            for (int kq = 0; kq < 4; ++kq) {
                float4 wv = w4p[kq];
                float wk[4] = {wv.x, wv.y, wv.z, wv.w};
#pragma unroll
                for (int tt = 0; tt < 4; ++tt) {
                    int k = kq * 4 + tt;
                    a0 += wk[tt] * qs[k * 4 + 0];
                    a1 += wk[tt] * qs[k * 4 + 1];
                    a2 += wk[tt] * qs[k * 4 + 2];
                    a3 += wk[tt] * qs[k * 4 + 3];
                }
            }
            a4[j] = make_float4(a0, a1, a2, a3);
        }
#pragma unroll
        for (int j = 0; j < 4; ++j) {
            if (v4[j]) {
                int b = d4[j] >> BKT_SHIFT;
                int slot = atomicAdd(&lhist[b], 1);
                s_sd[slot] = ((unsigned)d4[j] << 16) | (unsigned)s4[j];  // both < 65536
                s_ae4[slot] = a4[j];
                s_bkt[slot] = (unsigned char)b;
            }
        }
    }
    __syncthreads();
    // phase 4: coalesced flush LDS -> global (bucket-grouped order)
    for (int r = t; r < cnt_total; r += 256) {
        int b = s_bkt[r];
        int g = ldelta[b] + r;
        part_sd[g] = s_sd[r];
        part_ae4[g] = s_ae4[r];
    }
}

// ---------------------------------------------------------------- bucket scatter + per-node CSR

__global__ __launch_bounds__(256) void bucket_scatter_kernel(
    const unsigned* __restrict__ part_sd, const float4* __restrict__ part_ae4,
    const int* __restrict__ bbase, int* __restrict__ row_ptr, unsigned short* __restrict__ csr_src,
    float2* __restrict__ ae01, float* __restrict__ ae2, float* __restrict__ ae3, int N) {
    __shared__ int cnt[256];  // per-node counts -> scan -> cursors
    const int t = threadIdx.x;
    const int node0 = blockIdx.x << BKT_SHIFT;
    const int nend = min(node0 + 256, N);
    const int p0 = bbase[blockIdx.x];
    const int p1 = bbase[blockIdx.x + 1];
    cnt[t] = 0;
    __syncthreads();
    // pass 1: per-node histogram (4x unrolled)
    for (int pb = p0 + t; pb < p1; pb += 1024) {
        int d4[4];
        bool v4[4];
#pragma unroll
        for (int j = 0; j < 4; ++j) {
            int pp = pb + j * 256;
            v4[j] = pp < p1;
            d4[j] = (int)(part_sd[v4[j] ? pp : p0] >> 16);
        }
#pragma unroll
        for (int j = 0; j < 4; ++j)
            if (v4[j]) atomicAdd(&cnt[d4[j] - node0], 1);
    }
    __syncthreads();
    // scan -> row_ptr + cursors
    int c = cnt[t];
    __syncthreads();
    cnt[t] = c;
    __syncthreads();
    for (int off = 1; off < 256; off <<= 1) {
        int tmp = (t >= off) ? cnt[t - off] : 0;
        __syncthreads();
        cnt[t] += tmp;
        __syncthreads();
    }
    int excl = cnt[t] - c;
    if (node0 + t < nend) row_ptr[node0 + t] = p0 + excl;
    __syncthreads();
    cnt[t] = p0 + excl;  // cursor
    __syncthreads();
    // pass 2: scatter records (4x unrolled)
    for (int pb = p0 + t; pb < p1; pb += 1024) {
        unsigned sd4[4];
        float4 a4[4];
        bool v4[4];
#pragma unroll
        for (int j = 0; j < 4; ++j) {
            int pp = pb + j * 256;
            v4[j] = pp < p1;
            int pc = v4[j] ? pp : p0;
            sd4[j] = part_sd[pc];  // coalesced, L2-hot
            a4[j] = part_ae4[pc];  // coalesced
        }
#pragma unroll
        for (int j = 0; j < 4; ++j) {
            if (v4[j]) {
                int d = (int)(sd4[j] >> 16);
                int slot = atomicAdd(&cnt[d - node0], 1);
                csr_src[slot] = (unsigned short)(sd4[j] & 0xffffu);
                ae01[slot] = make_float2(a4[j].x, a4[j].y);
                ae2[slot] = a4[j].z;
                ae3[slot] = a4[j].w;
            }
        }
    }
}

// ---------------------------------------------------------------- MFMA node GEMM + alpha
// A-frag: row = lane&15, k = 32*kt + 8*(lane>>4) + j.  B-frag: col = lane&15, same k.
// C/D (m89-verified): col = lane&15, row = (lane>>4)*4 + reg.
// xwb: FP8 e4m3 message payload, PERMUTED per (node,head): col' = (c&15)*4 + (c>>4).

__device__ __forceinline__ bf16x8 bfrag_w(const float* __restrict__ W, int ldc, int k0, int c) {
    bf16x8 f;
#pragma unroll
    for (int j = 0; j < 8; ++j) f[j] = (short)f32_to_bf16u(W[(k0 + j) * ldc + c]);
    return f;
}

__device__ __forceinline__ bf16x8 afrag_f32(const float* __restrict__ row, int k0) {
    float4 u = *(const float4*)(row + k0);
    float4 v = *(const float4*)(row + k0 + 4);
    bf16x8 f;
    f[0] = (short)f32_to_bf16u(u.x);
    f[1] = (short)f32_to_bf16u(u.y);
    f[2] = (short)f32_to_bf16u(u.z);
    f[3] = (short)f32_to_bf16u(u.w);
    f[4] = (short)f32_to_bf16u(v.x);
    f[5] = (short)f32_to_bf16u(v.y);
    f[6] = (short)f32_to_bf16u(v.z);
    f[7] = (short)f32_to_bf16u(v.w);
    return f;
}

template <int H, bool ABF16>
__global__ __launch_bounds__(256) void xw_alpha_mfma_kernel(
    const float* __restrict__ xf, const unsigned short* __restrict__ xb,
    const float* __restrict__ W, const float* __restrict__ a_src, const float* __restrict__ a_dst,
    unsigned char* __restrict__ xwb, float* __restrict__ alpha_src,
    float* __restrict__ alpha_dst, int ntiles) {
    const int lane = threadIdx.x & 63;
    const int wv = threadIdx.x >> 6;
    const int tile = blockIdx.x * 4 + wv;
    if (tile >= ntiles) return;
    const int cl = lane & 15, kg = lane >> 4;
    const int n0 = tile * 16;

    bf16x8 bf[2][4 * H];
    float asr[4 * H], adr[4 * H];
#pragma unroll
    for (int kt = 0; kt < 2; ++kt)
#pragma unroll
        for (int ct = 0; ct < 4 * H; ++ct)
            bf[kt][ct] = bfrag_w(W, 64 * H, kt * 32 + kg * 8, ct * 16 + cl);
#pragma unroll
    for (int ct = 0; ct < 4 * H; ++ct) {
        int hh = ct >> 2;
        int c = (ct & 3) * 16 + cl;
        asr[ct] = a_src[hh * 64 + c];
        adr[ct] = a_dst[hh * 64 + c];
    }

    bf16x8 af0, af1;
    if (ABF16) {
        const unsigned short* rp = xb + (size_t)(n0 + cl) * 64;
        af0 = *(const bf16x8*)(rp + kg * 8);
        af1 = *(const bf16x8*)(rp + 32 + kg * 8);
    } else {
        const float* rp = xf + (size_t)(n0 + cl) * 64;
        af0 = afrag_f32(rp, kg * 8);
        af1 = afrag_f32(rp, 32 + kg * 8);
    }

    f32x4 acc[4 * H];
#pragma unroll
    for (int ct = 0; ct < 4 * H; ++ct) {
        f32x4 z = {0.f, 0.f, 0.f, 0.f};
        z = MFMA16(af0, bf[0][ct], z);
        acc[ct] = MFMA16(af1, bf[1][ct], z);
    }

    // store xwb (fp8, permuted layout): node r, head hh: uint (4 fp8) at col' = cl*4
#pragma unroll
    for (int r = 0; r < 4; ++r) {
        int n = n0 + kg * 4 + r;
#pragma unroll
        for (int hh = 0; hh < H; ++hh) {
            int pk = 0;
            pk = __builtin_amdgcn_cvt_pk_fp8_f32(acc[hh * 4 + 0][r], acc[hh * 4 + 1][r], pk,
                                                 false);
            pk = __builtin_amdgcn_cvt_pk_fp8_f32(acc[hh * 4 + 2][r], acc[hh * 4 + 3][r], pk,
                                                 true);
            *(unsigned*)(xwb + ((size_t)n * H + hh) * 64 + cl * 4) = (unsigned)pk;
        }
    }

    // alpha logits: dot over the 64 cols of head hh, reduced across the 16-lane group
#pragma unroll
    for (int hh = 0; hh < H; ++hh) {
#pragma unroll
        for (int r = 0; r < 4; ++r) {
            float vs = 0.f, vd = 0.f;
#pragma unroll
            for (int q = 0; q < 4; ++q) {
                vs += acc[hh * 4 + q][r] * asr[hh * 4 + q];
                vd += acc[hh * 4 + q][r] * adr[hh * 4 + q];
            }
#pragma unroll
            for (int off = 8; off; off >>= 1) {
                vs += __shfl_xor(vs, off, 16);
                vd += __shfl_xor(vd, off, 16);
            }
            if (cl == r) {
                int n = n0 + kg * 4 + r;
                alpha_src[n * H + hh] = vs;
                alpha_dst[n * H + hh] = vd;
            }
        }
    }
}

// readout: out[n][c] = sum_k x[n][k]*Wr[k][c] + br[c], fp32 out
__global__ __launch_bounds__(256) void readout_mfma_kernel(const unsigned short* __restrict__ xb,
                                                           const float* __restrict__ Wr,
                                                           const float* __restrict__ br,
                                                           float* __restrict__ out, int ntiles) {
    const int lane = threadIdx.x & 63;
    const int wv = threadIdx.x >> 6;
    const int tile = blockIdx.x * 4 + wv;
    if (tile >= ntiles) return;
    const int cl = lane & 15, kg = lane >> 4;
    const int n0 = tile * 16;

    bf16x8 bf[2][4];
    float brv[4];
#pragma unroll
    for (int kt = 0; kt < 2; ++kt)
#pragma unroll
        for (int ct = 0; ct < 4; ++ct) bf[kt][ct] = bfrag_w(Wr, 64, kt * 32 + kg * 8, ct * 16 + cl);
#pragma unroll
    for (int ct = 0; ct < 4; ++ct) brv[ct] = br[ct * 16 + cl];

    const unsigned short* rp = xb + (size_t)(n0 + cl) * 64;
    bf16x8 af0 = *(const bf16x8*)(rp + kg * 8);
    bf16x8 af1 = *(const bf16x8*)(rp + 32 + kg * 8);

    f32x4 acc[4];
#pragma unroll
    for (int ct = 0; ct < 4; ++ct) {
        f32x4 z = {0.f, 0.f, 0.f, 0.f};
        z = MFMA16(af0, bf[0][ct], z);
        acc[ct] = MFMA16(af1, bf[1][ct], z);
    }
#pragma unroll
    for (int r = 0; r < 4; ++r) {
        int n = n0 + kg * 4 + r;
#pragma unroll
        for (int ct = 0; ct < 4; ++ct) out[(size_t)n * 64 + ct * 16 + cl] = acc[ct][r] + brv[ct];
    }
}

// ---------------------------------------------------------------- aggregation
// 16-lane-group-per-node, fp8 payload (uint per lane = 4 fp8), SoA ae planes.

template <int H, int AEOFF>
__global__ __launch_bounds__(256) void aggregate16_kernel(
    const unsigned char* __restrict__ xwb, const float* __restrict__ alpha_src,
    const float* __restrict__ alpha_dst, const void* __restrict__ aeplane,
    const int* __restrict__ row_ptr, const unsigned short* __restrict__ csr_src,
    const float* __restrict__ bias, unsigned short* __restrict__ x_out, int N) {
    const int l = threadIdx.x & 15;    // sublane within group
    const int grp = threadIdx.x >> 4;  // group within block: 0..15
    const int n = blockIdx.x * 16 + grp;
    if (n >= N) return;
    const int base = row_ptr[n];
    const int deg = row_ptr[n + 1] - base;

    float bb[4];
#pragma unroll
    for (int q = 0; q < 4; ++q) bb[q] = bias[q * 16 + l];

    float m[H], den[H], o[H][4], ad[H];
#pragma unroll
    for (int h = 0; h < H; ++h) {
        m[h] = -1e30f;
        den[h] = 0.f;
        o[h][0] = o[h][1] = o[h][2] = o[h][3] = 0.f;
        ad[h] = alpha_dst[n * H + h];
    }

    for (int start = 0; start < deg; start += 16) {
        int j = start + l;
        bool act = j < deg;
        int s = 0;
        float a[H], ev[H];
        if (act) {
            s = csr_src[base + j];
            float asv[H], aev[H];
            if (H == 2) {
                float2 ae = ((const float2*)aeplane)[base + j];
                aev[0] = ae.x;
                aev[H - 1] = ae.y;
                float2 as2 = *((const float2*)alpha_src + s);
                asv[0] = as2.x;
                asv[H - 1] = as2.y;
            } else {
                aev[0] = ((const float*)aeplane)[base + j];
                asv[0] = alpha_src[s];
            }
#pragma unroll
            for (int h = 0; h < H; ++h) {
                float av = asv[h] + ad[h] + aev[h];
                a[h] = (av > 0.f) ? av : 0.2f * av;
            }
        } else {
#pragma unroll
            for (int h = 0; h < H; ++h) a[h] = -1e30f;
        }
        int cnt = min(deg - start, 16);
#pragma unroll
        for (int h = 0; h < H; ++h) {
            float cm = a[h];
#pragma unroll
            for (int off = 8; off; off >>= 1) cm = fmaxf(cm, __shfl_xor(cm, off, 16));
            float m_new = fmaxf(m[h], cm);
            float scale = __expf(m[h] - m_new);
            ev[h] = act ? __expf(a[h] - m_new) : 0.f;
            float cs = ev[h];
#pragma unroll
            for (int off = 8; off; off >>= 1) cs += __shfl_xor(cs, off, 16);
            den[h] = den[h] * scale + cs;
#pragma unroll
            for (int q = 0; q < 4; ++q) o[h][q] *= scale;
            m[h] = m_new;
        }
#pragma unroll 8
        for (int jj = 0; jj < cnt; ++jj) {
            int sj = __shfl(s, jj, 16);
#pragma unroll
            for (int h = 0; h < H; ++h) {
                float ej = __shfl(ev[h], jj, 16);
                unsigned v = *((const unsigned*)(xwb + ((size_t)sj * H + h) * 64) + l);
                f32x2 lo = __builtin_amdgcn_cvt_pk_f32_fp8((int)v, false);
                f32x2 hi = __builtin_amdgcn_cvt_pk_f32_fp8((int)v, true);
                o[h][0] += ej * lo[0];
                o[h][1] += ej * lo[1];
                o[h][2] += ej * hi[0];
                o[h][3] += ej * hi[1];
            }
        }
    }

#pragma unroll
    for (int q = 0; q < 4; ++q) {
        float acc = 0.f;
#pragma unroll
        for (int h = 0; h < H; ++h) acc += o[h][q] / (den[h] + 1e-16f);
        float r = acc * (H == 2 ? 0.5f : 1.f) + bb[q];
        r = r / (1.f + __expf(-r));  // silu
        x_out[(size_t)n * 64 + q * 16 + l] = f32_to_bf16u(r);  // un-permute: col = q*16+l
    }
}

// ---------------------------------------------------------------- launcher

static inline char* carve(char*& p, size_t bytes) {
    char* r = p;
    p += (bytes + 255) & ~(size_t)255;
    return r;
}

extern "C" void kernel_launch(void* const* d_in, const int* in_sizes, int n_in, void* d_out,
                              int out_size, void* d_ws, size_t ws_size, hipStream_t stream) {
    const int N = in_sizes[0] / IN_NODE;
    const int E = in_sizes[1] / IN_EDGE;

    const float* h = (const float*)d_in[0];
    const float* e = (const float*)d_in[1];
    const int* edge_index = (const int*)d_in[2];
    const float* w = (const float*)d_in[3];
    const float* W0 = (const float*)d_in[4];
    const float* as0 = (const float*)d_in[5];
    const float* ad0 = (const float*)d_in[6];
    const float* We0 = (const float*)d_in[7];
    const float* ae0 = (const float*)d_in[8];
    const float* b0 = (const float*)d_in[9];
    const float* W1 = (const float*)d_in[10];
    const float* as1 = (const float*)d_in[11];
    const float* ad1 = (const float*)d_in[12];
    const float* We1 = (const float*)d_in[13];
    const float* ae1 = (const float*)d_in[14];
    const float* b1 = (const float*)d_in[15];
    const float* W2 = (const float*)d_in[16];
    const float* as2 = (const float*)d_in[17];
    const float* ad2 = (const float*)d_in[18];
    const float* We2 = (const float*)d_in[19];
    const float* ae2 = (const float*)d_in[20];
    const float* b2 = (const float*)d_in[21];
    const float* Wr = (const float*)d_in[22];
    const float* br = (const float*)d_in[23];

    const int* src = edge_index;
    const int* dst = edge_index + E;

    float* out_x = (float*)d_out;                        // [N,64]
    float* out_e = (float*)d_out + (size_t)N * IN_NODE;  // [E,16] passthrough

    char* p = (char*)d_ws;
    unsigned char* xwb = (unsigned char*)carve(p, (size_t)N * 128);      // fp8 [N,H,64] perm
    unsigned short* xA = (unsigned short*)carve(p, (size_t)N * 64 * 2);  // bf16 [N,64]
    unsigned short* xB = (unsigned short*)carve(p, (size_t)N * 64 * 2);  // bf16 [N,64]
    float* csr_ae01 = (float*)carve(p, (size_t)E * 2 * 4);  // SoA logit planes
    float* csr_ae2 = (float*)carve(p, (size_t)E * 4);
    float* csr_ae3 = (float*)carve(p, (size_t)E * 4);
    float* a_src = (float*)carve(p, (size_t)N * 2 * 4);
    float* a_dst = (float*)carve(p, (size_t)N * 2 * 4);
    float* qall = (float*)carve(p, 64 * 4);
    int* row_ptr = (int*)carve(p, (size_t)(N + 1) * 4);
    int* btot = (int*)carve(p, 256 * 4);
    int* bbase = (int*)carve(p, 257 * 4);
    unsigned short* csr_src = (unsigned short*)carve(p, (size_t)E * 2);
    unsigned* part_sd = (unsigned*)carve(p, (size_t)E * 4);
    float* part_ae4 = (float*)carve(p, (size_t)E * 4 * 4);
    int* gbcur = (int*)carve(p, 1024 * 4);

    const int ngrid16 = (N + 15) / 16;
    const int NBK = (N + 255) >> BKT_SHIFT;             // dst-node buckets of 256
    const int PART_BLOCKS = (E + PART_T - 1) / PART_T;  // 512 blocks @ PART_T=1563
    const int ntiles = (N + 15) / 16;                   // 16-node MFMA tiles
    const int ggrid = (ntiles + 3) / 4;                 // 4 waves/block, 1 tile/wave
    const int n4 = E * IN_EDGE / 4;                     // e passthrough float4 count

    // bucket-granularity CSR prologue; e-copy rides in btot (high-occupancy stream)
    hipMemsetAsync(btot, 0, 256 * 4, stream);
    btot_kernel<<<512, 256, 0, stream>>>(dst, btot, (const float4*)e, (float4*)out_e, n4, E, NBK);
    scan_btot_kernel<<<1, 256, 0, stream>>>(btot, bbase, gbcur, row_ptr, We0, ae0, We1, ae1, We2,
                                            ae2, qall, NBK, N, E);

    // LDS-staged partition (logits fused) + bucket scatter (builds row_ptr)
    partition_kernel<<<PART_BLOCKS, 256, 0, stream>>>(dst, src, w, qall, gbcur, part_sd,
                                                      (float4*)part_ae4, E, NBK);
    bucket_scatter_kernel<<<NBK, 256, 0, stream>>>(part_sd, (const float4*)part_ae4, bbase,
                                                   row_ptr, csr_src, (float2*)csr_ae01, csr_ae2,
                                                   csr_ae3, N);

    // layer 0 (H=2), input h fp32
    xw_alpha_mfma_kernel<2, false><<<ggrid, 256, 0, stream>>>(h, nullptr, W0, as0, ad0, xwb, a_src,
                                                              a_dst, ntiles);
    aggregate16_kernel<2, 0><<<ngrid16, 256, 0, stream>>>(xwb, a_src, a_dst, csr_ae01, row_ptr,
                                                          csr_src, b0, xA, N);
    // layer 1 (H=1), input xA bf16
    xw_alpha_mfma_kernel<1, true><<<ggrid, 256, 0, stream>>>(nullptr, xA, W1, as1, ad1, xwb, a_src,
                                                             a_dst, ntiles);
    aggregate16_kernel<1, 2><<<ngrid16, 256, 0, stream>>>(xwb, a_src, a_dst, csr_ae2, row_ptr,
                                                          csr_src, b1, xB, N);
    // layer 2 (H=1), input xB bf16
    xw_alpha_mfma_kernel<1, true><<<ggrid, 256, 0, stream>>>(nullptr, xB, W2, as2, ad2, xwb, a_src,
                                                             a_dst, ntiles);
    aggregate16_kernel<1, 3><<<ngrid16, 256, 0, stream>>>(xwb, a_src, a_dst, csr_ae3, row_ptr,
                                                          csr_src, b2, xA, N);
    // readout, input xA bf16
    readout_mfma_kernel<<<ggrid, 256, 0, stream>>>(xA, Wr, br, out_x, ntiles);
}

// Round 20
// 198.255 us; speedup vs baseline: 1.0695x; 1.0090x over previous
//
#include <hip/hip_runtime.h>
#include <hip/hip_bf16.h>

#define IN_NODE 64
#define IN_EDGE 16
#define HID 64
#define BKT_SHIFT 8     // 256 dst-nodes per bucket
#define PART_T 1563     // edges per partition block (proven best, R13-R17)
#define PART_TMAX 1600  // LDS record capacity (>= PART_T)
#define HIST_BLOCKS 64  // btot partial-histogram blocks (no-init accumulation)

using f32x4 = __attribute__((ext_vector_type(4))) float;
using f32x2 = __attribute__((ext_vector_type(2))) float;
using bf16x8 = __attribute__((ext_vector_type(8))) short;
#define MFMA16(a, b, c) __builtin_amdgcn_mfma_f32_16x16x32_bf16(a, b, c, 0, 0, 0)

__device__ __forceinline__ unsigned short f32_to_bf16u(float f) {
    __hip_bfloat16 hb = __float2bfloat16(f);
    return *(unsigned short*)&hb;
}
__device__ __forceinline__ float bf16u_to_f32(unsigned short u) {
    return __uint_as_float(((unsigned)u) << 16);
}

// ---------------------------------------------------------------- bucket-granularity CSR prologue
// No-memset design: first HIST_BLOCKS blocks write per-block partial histograms
// (every slot written, so no zero-init needed — removes the hipMemsetAsync that
// profiled at ~40us). All blocks carry the e-passthrough copy, 4x unrolled for MLP.

__global__ __launch_bounds__(256) void btot_kernel(const int* __restrict__ dst,
                                                   int* __restrict__ part,
                                                   const float4* __restrict__ e4,
                                                   float4* __restrict__ out_e4, int n4, int E,
                                                   int NBK) {
    __shared__ int lhist[256];
    const int t = threadIdx.x;
    const int bid = blockIdx.x;
    if (bid < HIST_BLOCKS) {
        lhist[t] = 0;
        __syncthreads();
        const int chunk = (E + HIST_BLOCKS - 1) / HIST_BLOCKS;
        const int e0 = bid * chunk;
        const int e1 = min(e0 + chunk, E);
        for (int e = e0 + t; e < e1; e += 256) atomicAdd(&lhist[dst[e] >> BKT_SHIFT], 1);
        __syncthreads();
        part[bid * 256 + t] = lhist[t];  // non-atomic, every slot written
    }
    // e passthrough (grid-stride, 4x batched loads then stores for MLP)
    const int stride = gridDim.x * 1024;
    for (int ib = bid * 1024 + t; ib < n4 + 768; ib += stride) {
        float4 v[4];
        bool val[4];
#pragma unroll
        for (int j = 0; j < 4; ++j) {
            int idx = ib + j * 256;
            val[j] = idx < n4;
            v[j] = val[j] ? e4[idx] : make_float4(0.f, 0.f, 0.f, 0.f);
        }
#pragma unroll
        for (int j = 0; j < 4; ++j)
            if (val[j]) out_e4[ib + j * 256] = v[j];
    }
}

// single block: reduce partials -> btot; bbase = exclusive scan; seed gbcur;
// row_ptr[N]=E; q-vector prep on lanes t<64.
__global__ __launch_bounds__(256) void scan_btot_kernel(
    const int* __restrict__ part, int* __restrict__ bbase, int* __restrict__ gbcur,
    int* __restrict__ row_ptr, const float* __restrict__ We0, const float* __restrict__ ae0,
    const float* __restrict__ We1, const float* __restrict__ ae1, const float* __restrict__ We2,
    const float* __restrict__ ae2, float* __restrict__ q, int NBK, int N, int E) {
    __shared__ int sd[256];
    int t = threadIdx.x;
    int v = 0;
#pragma unroll 4
    for (int b = 0; b < HIST_BLOCKS; ++b) v += part[b * 256 + t];
    if (t >= NBK) v = 0;
    sd[t] = v;
    __syncthreads();
    for (int off = 1; off < 256; off <<= 1) {
        int tmp = (t >= off) ? sd[t - off] : 0;
        __syncthreads();
        sd[t] += tmp;
        __syncthreads();
    }
    int excl = sd[t] - v;
    if (t < NBK) {
        bbase[t] = excl;
        gbcur[t] = excl;
    }
    if (t == NBK - 1) bbase[NBK] = sd[t];
    if (t == 0) row_ptr[N] = E;
    // q prep (no barriers below — divergence safe)
    if (t < 32) {
        int k = t >> 1, hh = t & 1;
        float s = 0.f;
        for (int c = 0; c < HID; ++c) s += We0[k * 128 + hh * 64 + c] * ae0[hh * 64 + c];
        q[k * 4 + hh] = s;
    } else if (t < 48) {
        int k = t - 32;
        float s = 0.f;
        for (int c = 0; c < HID; ++c) s += We1[k * 64 + c] * ae1[c];
        q[k * 4 + 2] = s;
    } else if (t < 64) {
        int k = t - 48;
        float s = 0.f;
        for (int c = 0; c < HID; ++c) s += We2[k * 64 + c] * ae2[c];
        q[k * 4 + 3] = s;
    }
}

// ---------------------------------------------------------------- LDS-staged radix partition

__global__ __launch_bounds__(256) void partition_kernel(
    const int* __restrict__ dst, const int* __restrict__ src, const float* __restrict__ w,
    const float* __restrict__ q, int* __restrict__ gbcur, unsigned* __restrict__ part_sd,
    float4* __restrict__ part_ae4, int E, int NBK) {
    __shared__ int lhist[256];   // counts -> cursor
    __shared__ int ldelta[256];  // global_base - lds_base per bucket
    __shared__ float qs[64];
    __shared__ unsigned s_sd[PART_TMAX];
    __shared__ float4 s_ae4[PART_TMAX];
    __shared__ unsigned char s_bkt[PART_TMAX];
    const int t = threadIdx.x;
    const int e0 = blockIdx.x * PART_T;
    const int e1 = min(e0 + PART_T, E);
    const int cnt_total = e1 - e0;
    if (t < 64) qs[t] = q[t];
    lhist[t] = 0;
    __syncthreads();
    // phase 1: histogram (4x unrolled)
    for (int eb = e0 + t; eb < e1; eb += 1024) {
        int b4[4];
        bool v4[4];
#pragma unroll
        for (int j = 0; j < 4; ++j) {
            int e = eb + j * 256;
            v4[j] = e < e1;
            b4[j] = dst[v4[j] ? e : e0] >> BKT_SHIFT;
        }
#pragma unroll
        for (int j = 0; j < 4; ++j)
            if (v4[j]) atomicAdd(&lhist[b4[j]], 1);
    }
    __syncthreads();
    // phase 2: block exclusive scan of lhist -> LDS base; reserve global ranges
    int cnt = lhist[t];
    __syncthreads();
    lhist[t] = cnt;
    __syncthreads();
    for (int off = 1; off < 256; off <<= 1) {
        int tmp = (t >= off) ? lhist[t - off] : 0;
        __syncthreads();
        lhist[t] += tmp;
        __syncthreads();
    }
    int lbase = lhist[t] - cnt;  // exclusive
    int gbase = (t < NBK && cnt) ? atomicAdd(&gbcur[t], cnt) : 0;
    ldelta[t] = gbase - lbase;
    __syncthreads();
    lhist[t] = lbase;  // becomes the LDS cursor
    __syncthreads();
    // phase 3: compute logits + write records into LDS, bucket-grouped (4x unrolled)
    for (int eb = e0 + t; eb < e1; eb += 1024) {
        int d4[4], s4[4];
        bool v4[4];
        float4 a4[4];
#pragma unroll
        for (int j = 0; j < 4; ++j) {
            int e = eb + j * 256;
            v4[j] = e < e1;
            int ec = v4[j] ? e : e0;
            d4[j] = dst[ec];
            s4[j] = src[ec];
            const float4* w4p = (const float4*)(w + (size_t)ec * IN_EDGE);
            float a0 = 0.f, a1 = 0.f, a2 = 0.f, a3 = 0.f;
#pragma unroll
            for (int kq = 0; kq < 4; ++kq) {
                float4 wv = w4p[kq];
                float wk[4] = {wv.x, wv.y, wv.z, wv.w};
#pragma unroll
                for (int tt = 0; tt < 4; ++tt) {
                    int k = kq * 4 + tt;
                    a0 += wk[tt] * qs[k * 4 + 0];
                    a1 += wk[tt] * qs[k * 4 + 1];
                    a2 += wk[tt] * qs[k * 4 + 2];
                    a3 += wk[tt] * qs[k * 4 + 3];
                }
            }
            a4[j] = make_float4(a0, a1, a2, a3);
        }
#pragma unroll
        for (int j = 0; j < 4; ++j) {
            if (v4[j]) {
                int b = d4[j] >> BKT_SHIFT;
                int slot = atomicAdd(&lhist[b], 1);
                s_sd[slot] = ((unsigned)d4[j] << 16) | (unsigned)s4[j];  // both < 65536
                s_ae4[slot] = a4[j];
                s_bkt[slot] = (unsigned char)b;
            }
        }
    }
    __syncthreads();
    // phase 4: coalesced flush LDS -> global (bucket-grouped order)
    for (int r = t; r < cnt_total; r += 256) {
        int b = s_bkt[r];
        int g = ldelta[b] + r;
        part_sd[g] = s_sd[r];
        part_ae4[g] = s_ae4[r];
    }
}

// ---------------------------------------------------------------- bucket scatter + per-node CSR

__global__ __launch_bounds__(256) void bucket_scatter_kernel(
    const unsigned* __restrict__ part_sd, const float4* __restrict__ part_ae4,
    const int* __restrict__ bbase, int* __restrict__ row_ptr, unsigned short* __restrict__ csr_src,
    float2* __restrict__ ae01, float* __restrict__ ae2, float* __restrict__ ae3, int N) {
    __shared__ int cnt[256];  // per-node counts -> scan -> cursors
    const int t = threadIdx.x;
    const int node0 = blockIdx.x << BKT_SHIFT;
    const int nend = min(node0 + 256, N);
    const int p0 = bbase[blockIdx.x];
    const int p1 = bbase[blockIdx.x + 1];
    cnt[t] = 0;
    __syncthreads();
    // pass 1: per-node histogram (4x unrolled)
    for (int pb = p0 + t; pb < p1; pb += 1024) {
        int d4[4];
        bool v4[4];
#pragma unroll
        for (int j = 0; j < 4; ++j) {
            int pp = pb + j * 256;
            v4[j] = pp < p1;
            d4[j] = (int)(part_sd[v4[j] ? pp : p0] >> 16);
        }
#pragma unroll
        for (int j = 0; j < 4; ++j)
            if (v4[j]) atomicAdd(&cnt[d4[j] - node0], 1);
    }
    __syncthreads();
    // scan -> row_ptr + cursors
    int c = cnt[t];
    __syncthreads();
    cnt[t] = c;
    __syncthreads();
    for (int off = 1; off < 256; off <<= 1) {
        int tmp = (t >= off) ? cnt[t - off] : 0;
        __syncthreads();
        cnt[t] += tmp;
        __syncthreads();
    }
    int excl = cnt[t] - c;
    if (node0 + t < nend) row_ptr[node0 + t] = p0 + excl;
    __syncthreads();
    cnt[t] = p0 + excl;  // cursor
    __syncthreads();
    // pass 2: scatter records (4x unrolled)
    for (int pb = p0 + t; pb < p1; pb += 1024) {
        unsigned sd4[4];
        float4 a4[4];
        bool v4[4];
#pragma unroll
        for (int j = 0; j < 4; ++j) {
            int pp = pb + j * 256;
            v4[j] = pp < p1;
            int pc = v4[j] ? pp : p0;
            sd4[j] = part_sd[pc];  // coalesced, L2-hot
            a4[j] = part_ae4[pc];  // coalesced
        }
#pragma unroll
        for (int j = 0; j < 4; ++j) {
            if (v4[j]) {
                int d = (int)(sd4[j] >> 16);
                int slot = atomicAdd(&cnt[d - node0], 1);
                csr_src[slot] = (unsigned short)(sd4[j] & 0xffffu);
                ae01[slot] = make_float2(a4[j].x, a4[j].y);
                ae2[slot] = a4[j].z;
                ae3[slot] = a4[j].w;
            }
        }
    }
}

// ---------------------------------------------------------------- MFMA node GEMM + alpha
// A-frag: row = lane&15, k = 32*kt + 8*(lane>>4) + j.  B-frag: col = lane&15, same k.
// C/D (m89-verified): col = lane&15, row = (lane>>4)*4 + reg.
// xwb: FP8 e4m3 message payload, PERMUTED per (node,head): col' = (c&15)*4 + (c>>4).

__device__ __forceinline__ bf16x8 bfrag_w(const float* __restrict__ W, int ldc, int k0, int c) {
    bf16x8 f;
#pragma unroll
    for (int j = 0; j < 8; ++j) f[j] = (short)f32_to_bf16u(W[(k0 + j) * ldc + c]);
    return f;
}

__device__ __forceinline__ bf16x8 afrag_f32(const float* __restrict__ row, int k0) {
    float4 u = *(const float4*)(row + k0);
    float4 v = *(const float4*)(row + k0 + 4);
    bf16x8 f;
    f[0] = (short)f32_to_bf16u(u.x);
    f[1] = (short)f32_to_bf16u(u.y);
    f[2] = (short)f32_to_bf16u(u.z);
    f[3] = (short)f32_to_bf16u(u.w);
    f[4] = (short)f32_to_bf16u(v.x);
    f[5] = (short)f32_to_bf16u(v.y);
    f[6] = (short)f32_to_bf16u(v.z);
    f[7] = (short)f32_to_bf16u(v.w);
    return f;
}

template <int H, bool ABF16>
__global__ __launch_bounds__(256) void xw_alpha_mfma_kernel(
    const float* __restrict__ xf, const unsigned short* __restrict__ xb,
    const float* __restrict__ W, const float* __restrict__ a_src, const float* __restrict__ a_dst,
    unsigned char* __restrict__ xwb, float* __restrict__ alpha_src,
    float* __restrict__ alpha_dst, int ntiles) {
    const int lane = threadIdx.x & 63;
    const int wv = threadIdx.x >> 6;
    const int tile = blockIdx.x * 4 + wv;
    if (tile >= ntiles) return;
    const int cl = lane & 15, kg = lane >> 4;
    const int n0 = tile * 16;

    bf16x8 bf[2][4 * H];
    float asr[4 * H], adr[4 * H];
#pragma unroll
    for (int kt = 0; kt < 2; ++kt)
#pragma unroll
        for (int ct = 0; ct < 4 * H; ++ct)
            bf[kt][ct] = bfrag_w(W, 64 * H, kt * 32 + kg * 8, ct * 16 + cl);
#pragma unroll
    for (int ct = 0; ct < 4 * H; ++ct) {
        int hh = ct >> 2;
        int c = (ct & 3) * 16 + cl;
        asr[ct] = a_src[hh * 64 + c];
        adr[ct] = a_dst[hh * 64 + c];
    }

    bf16x8 af0, af1;
    if (ABF16) {
        const unsigned short* rp = xb + (size_t)(n0 + cl) * 64;
        af0 = *(const bf16x8*)(rp + kg * 8);
        af1 = *(const bf16x8*)(rp + 32 + kg * 8);
    } else {
        const float* rp = xf + (size_t)(n0 + cl) * 64;
        af0 = afrag_f32(rp, kg * 8);
        af1 = afrag_f32(rp, 32 + kg * 8);
    }

    f32x4 acc[4 * H];
#pragma unroll
    for (int ct = 0; ct < 4 * H; ++ct) {
        f32x4 z = {0.f, 0.f, 0.f, 0.f};
        z = MFMA16(af0, bf[0][ct], z);
        acc[ct] = MFMA16(af1, bf[1][ct], z);
    }

    // store xwb (fp8, permuted layout): node r, head hh: uint (4 fp8) at col' = cl*4
#pragma unroll
    for (int r = 0; r < 4; ++r) {
        int n = n0 + kg * 4 + r;
#pragma unroll
        for (int hh = 0; hh < H; ++hh) {
            int pk = 0;
            pk = __builtin_amdgcn_cvt_pk_fp8_f32(acc[hh * 4 + 0][r], acc[hh * 4 + 1][r], pk,
                                                 false);
            pk = __builtin_amdgcn_cvt_pk_fp8_f32(acc[hh * 4 + 2][r], acc[hh * 4 + 3][r], pk,
                                                 true);
            *(unsigned*)(xwb + ((size_t)n * H + hh) * 64 + cl * 4) = (unsigned)pk;
        }
    }

    // alpha logits: dot over the 64 cols of head hh, reduced across the 16-lane group
#pragma unroll
    for (int hh = 0; hh < H; ++hh) {
#pragma unroll
        for (int r = 0; r < 4; ++r) {
            float vs = 0.f, vd = 0.f;
#pragma unroll
            for (int q = 0; q < 4; ++q) {
                vs += acc[hh * 4 + q][r] * asr[hh * 4 + q];
                vd += acc[hh * 4 + q][r] * adr[hh * 4 + q];
            }
#pragma unroll
            for (int off = 8; off; off >>= 1) {
                vs += __shfl_xor(vs, off, 16);
                vd += __shfl_xor(vd, off, 16);
            }
            if (cl == r) {
                int n = n0 + kg * 4 + r;
                alpha_src[n * H + hh] = vs;
                alpha_dst[n * H + hh] = vd;
            }
        }
    }
}

// readout: out[n][c] = sum_k x[n][k]*Wr[k][c] + br[c], fp32 out
__global__ __launch_bounds__(256) void readout_mfma_kernel(const unsigned short* __restrict__ xb,
                                                           const float* __restrict__ Wr,
                                                           const float* __restrict__ br,
                                                           float* __restrict__ out, int ntiles) {
    const int lane = threadIdx.x & 63;
    const int wv = threadIdx.x >> 6;
    const int tile = blockIdx.x * 4 + wv;
    if (tile >= ntiles) return;
    const int cl = lane & 15, kg = lane >> 4;
    const int n0 = tile * 16;

    bf16x8 bf[2][4];
    float brv[4];
#pragma unroll
    for (int kt = 0; kt < 2; ++kt)
#pragma unroll
        for (int ct = 0; ct < 4; ++ct) bf[kt][ct] = bfrag_w(Wr, 64, kt * 32 + kg * 8, ct * 16 + cl);
#pragma unroll
    for (int ct = 0; ct < 4; ++ct) brv[ct] = br[ct * 16 + cl];

    const unsigned short* rp = xb + (size_t)(n0 + cl) * 64;
    bf16x8 af0 = *(const bf16x8*)(rp + kg * 8);
    bf16x8 af1 = *(const bf16x8*)(rp + 32 + kg * 8);

    f32x4 acc[4];
#pragma unroll
    for (int ct = 0; ct < 4; ++ct) {
        f32x4 z = {0.f, 0.f, 0.f, 0.f};
        z = MFMA16(af0, bf[0][ct], z);
        acc[ct] = MFMA16(af1, bf[1][ct], z);
    }
#pragma unroll
    for (int r = 0; r < 4; ++r) {
        int n = n0 + kg * 4 + r;
#pragma unroll
        for (int ct = 0; ct < 4; ++ct) out[(size_t)n * 64 + ct * 16 + cl] = acc[ct][r] + brv[ct];
    }
}

// ---------------------------------------------------------------- aggregation
// 16-lane-group-per-node, fp8 payload (uint per lane = 4 fp8), SoA ae planes.

template <int H, int AEOFF>
__global__ __launch_bounds__(256) void aggregate16_kernel(
    const unsigned char* __restrict__ xwb, const float* __restrict__ alpha_src,
    const float* __restrict__ alpha_dst, const void* __restrict__ aeplane,
    const int* __restrict__ row_ptr, const unsigned short* __restrict__ csr_src,
    const float* __restrict__ bias, unsigned short* __restrict__ x_out, int N) {
    const int l = threadIdx.x & 15;    // sublane within group
    const int grp = threadIdx.x >> 4;  // group within block: 0..15
    const int n = blockIdx.x * 16 + grp;
    if (n >= N) return;
    const int base = row_ptr[n];
    const int deg = row_ptr[n + 1] - base;

    float bb[4];
#pragma unroll
    for (int q = 0; q < 4; ++q) bb[q] = bias[q * 16 + l];

    float m[H], den[H], o[H][4], ad[H];
#pragma unroll
    for (int h = 0; h < H; ++h) {
        m[h] = -1e30f;
        den[h] = 0.f;
        o[h][0] = o[h][1] = o[h][2] = o[h][3] = 0.f;
        ad[h] = alpha_dst[n * H + h];
    }

    for (int start = 0; start < deg; start += 16) {
        int j = start + l;
        bool act = j < deg;
        int s = 0;
        float a[H], ev[H];
        if (act) {
            s = csr_src[base + j];
            float asv[H], aev[H];
            if (H == 2) {
                float2 ae = ((const float2*)aeplane)[base + j];
                aev[0] = ae.x;
                aev[H - 1] = ae.y;
                float2 as2 = *((const float2*)alpha_src + s);
                asv[0] = as2.x;
                asv[H - 1] = as2.y;
            } else {
                aev[0] = ((const float*)aeplane)[base + j];
                asv[0] = alpha_src[s];
            }
#pragma unroll
            for (int h = 0; h < H; ++h) {
                float av = asv[h] + ad[h] + aev[h];
                a[h] = (av > 0.f) ? av : 0.2f * av;
            }
        } else {
#pragma unroll
            for (int h = 0; h < H; ++h) a[h] = -1e30f;
        }
        int cnt = min(deg - start, 16);
#pragma unroll
        for (int h = 0; h < H; ++h) {
            float cm = a[h];
#pragma unroll
            for (int off = 8; off; off >>= 1) cm = fmaxf(cm, __shfl_xor(cm, off, 16));
            float m_new = fmaxf(m[h], cm);
            float scale = __expf(m[h] - m_new);
            ev[h] = act ? __expf(a[h] - m_new) : 0.f;
            float cs = ev[h];
#pragma unroll
            for (int off = 8; off; off >>= 1) cs += __shfl_xor(cs, off, 16);
            den[h] = den[h] * scale + cs;
#pragma unroll
            for (int q = 0; q < 4; ++q) o[h][q] *= scale;
            m[h] = m_new;
        }
#pragma unroll 8
        for (int jj = 0; jj < cnt; ++jj) {
            int sj = __shfl(s, jj, 16);
#pragma unroll
            for (int h = 0; h < H; ++h) {
                float ej = __shfl(ev[h], jj, 16);
                unsigned v = *((const unsigned*)(xwb + ((size_t)sj * H + h) * 64) + l);
                f32x2 lo = __builtin_amdgcn_cvt_pk_f32_fp8((int)v, false);
                f32x2 hi = __builtin_amdgcn_cvt_pk_f32_fp8((int)v, true);
                o[h][0] += ej * lo[0];
                o[h][1] += ej * lo[1];
                o[h][2] += ej * hi[0];
                o[h][3] += ej * hi[1];
            }
        }
    }

#pragma unroll
    for (int q = 0; q < 4; ++q) {
        float acc = 0.f;
#pragma unroll
        for (int h = 0; h < H; ++h) acc += o[h][q] / (den[h] + 1e-16f);
        float r = acc * (H == 2 ? 0.5f : 1.f) + bb[q];
        r = r / (1.f + __expf(-r));  // silu
        x_out[(size_t)n * 64 + q * 16 + l] = f32_to_bf16u(r);  // un-permute: col = q*16+l
    }
}

// ---------------------------------------------------------------- launcher

static inline char* carve(char*& p, size_t bytes) {
    char* r = p;
    p += (bytes + 255) & ~(size_t)255;
    return r;
}

extern "C" void kernel_launch(void* const* d_in, const int* in_sizes, int n_in, void* d_out,
                              int out_size, void* d_ws, size_t ws_size, hipStream_t stream) {
    const int N = in_sizes[0] / IN_NODE;
    const int E = in_sizes[1] / IN_EDGE;

    const float* h = (const float*)d_in[0];
    const float* e = (const float*)d_in[1];
    const int* edge_index = (const int*)d_in[2];
    const float* w = (const float*)d_in[3];
    const float* W0 = (const float*)d_in[4];
    const float* as0 = (const float*)d_in[5];
    const float* ad0 = (const float*)d_in[6];
    const float* We0 = (const float*)d_in[7];
    const float* ae0 = (const float*)d_in[8];
    const float* b0 = (const float*)d_in[9];
    const float* W1 = (const float*)d_in[10];
    const float* as1 = (const float*)d_in[11];
    const float* ad1 = (const float*)d_in[12];
    const float* We1 = (const float*)d_in[13];
    const float* ae1 = (const float*)d_in[14];
    const float* b1 = (const float*)d_in[15];
    const float* W2 = (const float*)d_in[16];
    const float* as2 = (const float*)d_in[17];
    const float* ad2 = (const float*)d_in[18];
    const float* We2 = (const float*)d_in[19];
    const float* ae2 = (const float*)d_in[20];
    const float* b2 = (const float*)d_in[21];
    const float* Wr = (const float*)d_in[22];
    const float* br = (const float*)d_in[23];

    const int* src = edge_index;
    const int* dst = edge_index + E;

    float* out_x = (float*)d_out;                        // [N,64]
    float* out_e = (float*)d_out + (size_t)N * IN_NODE;  // [E,16] passthrough

    char* p = (char*)d_ws;
    unsigned char* xwb = (unsigned char*)carve(p, (size_t)N * 128);      // fp8 [N,H,64] perm
    unsigned short* xA = (unsigned short*)carve(p, (size_t)N * 64 * 2);  // bf16 [N,64]
    unsigned short* xB = (unsigned short*)carve(p, (size_t)N * 64 * 2);  // bf16 [N,64]
    float* csr_ae01 = (float*)carve(p, (size_t)E * 2 * 4);  // SoA logit planes
    float* csr_ae2 = (float*)carve(p, (size_t)E * 4);
    float* csr_ae3 = (float*)carve(p, (size_t)E * 4);
    float* a_src = (float*)carve(p, (size_t)N * 2 * 4);
    float* a_dst = (float*)carve(p, (size_t)N * 2 * 4);
    float* qall = (float*)carve(p, 64 * 4);
    int* row_ptr = (int*)carve(p, (size_t)(N + 1) * 4);
    int* hist_part = (int*)carve(p, HIST_BLOCKS * 256 * 4);  // no-init partials
    int* bbase = (int*)carve(p, 257 * 4);
    unsigned short* csr_src = (unsigned short*)carve(p, (size_t)E * 2);
    unsigned* part_sd = (unsigned*)carve(p, (size_t)E * 4);
    float* part_ae4 = (float*)carve(p, (size_t)E * 4 * 4);
    int* gbcur = (int*)carve(p, 1024 * 4);

    const int ngrid16 = (N + 15) / 16;
    const int NBK = (N + 255) >> BKT_SHIFT;             // dst-node buckets of 256
    const int PART_BLOCKS = (E + PART_T - 1) / PART_T;  // 512 blocks @ PART_T=1563
    const int ntiles = (N + 15) / 16;                   // 16-node MFMA tiles
    const int ggrid = (ntiles + 3) / 4;                 // 4 waves/block, 1 tile/wave
    const int n4 = E * IN_EDGE / 4;                     // e passthrough float4 count

    // bucket-granularity CSR prologue (no memset; partial-hist accumulation);
    // e-copy rides in btot (high-occupancy stream, 4x-unrolled)
    btot_kernel<<<512, 256, 0, stream>>>(dst, hist_part, (const float4*)e, (float4*)out_e, n4, E,
                                         NBK);
    scan_btot_kernel<<<1, 256, 0, stream>>>(hist_part, bbase, gbcur, row_ptr, We0, ae0, We1, ae1,
                                            We2, ae2, qall, NBK, N, E);

    // LDS-staged partition (logits fused) + bucket scatter (builds row_ptr)
    partition_kernel<<<PART_BLOCKS, 256, 0, stream>>>(dst, src, w, qall, gbcur, part_sd,
                                                      (float4*)part_ae4, E, NBK);
    bucket_scatter_kernel<<<NBK, 256, 0, stream>>>(part_sd, (const float4*)part_ae4, bbase,
                                                   row_ptr, csr_src, (float2*)csr_ae01, csr_ae2,
                                                   csr_ae3, N);

    // layer 0 (H=2), input h fp32
    xw_alpha_mfma_kernel<2, false><<<ggrid, 256, 0, stream>>>(h, nullptr, W0, as0, ad0, xwb, a_src,
                                                              a_dst, ntiles);
    aggregate16_kernel<2, 0><<<ngrid16, 256, 0, stream>>>(xwb, a_src, a_dst, csr_ae01, row_ptr,
                                                          csr_src, b0, xA, N);
    // layer 1 (H=1), input xA bf16
    xw_alpha_mfma_kernel<1, true><<<ggrid, 256, 0, stream>>>(nullptr, xA, W1, as1, ad1, xwb, a_src,
                                                             a_dst, ntiles);
    aggregate16_kernel<1, 2><<<ngrid16, 256, 0, stream>>>(xwb, a_src, a_dst, csr_ae2, row_ptr,
                                                          csr_src, b1, xB, N);
    // layer 2 (H=1), input xB bf16
    xw_alpha_mfma_kernel<1, true><<<ggrid, 256, 0, stream>>>(nullptr, xB, W2, as2, ad2, xwb, a_src,
                                                             a_dst, ntiles);
    aggregate16_kernel<1, 3><<<ngrid16, 256, 0, stream>>>(xwb, a_src, a_dst, csr_ae3, row_ptr,
                                                          csr_src, b2, xA, N);
    // readout, input xA bf16
    readout_mfma_kernel<<<ggrid, 256, 0, stream>>>(xA, Wr, br, out_x, ntiles);
}

// Round 21
// 195.978 us; speedup vs baseline: 1.0819x; 1.0116x over previous
//
#include <hip/hip_runtime.h>
#include <hip/hip_bf16.h>

#define IN_NODE 64
#define IN_EDGE 16
#define HID 64
#define BKT_SHIFT 8     // 256 dst-nodes per bucket
#define PART_T 1563     // edges per partition block (proven best, R13-R17)
#define PART_TMAX 1600  // LDS record capacity (>= PART_T)
#define HIST_BLOCKS 64  // btot partial-histogram blocks (no-init accumulation)

using f32x4 = __attribute__((ext_vector_type(4))) float;
using f32x2 = __attribute__((ext_vector_type(2))) float;
using bf16x8 = __attribute__((ext_vector_type(8))) short;
#define MFMA16(a, b, c) __builtin_amdgcn_mfma_f32_16x16x32_bf16(a, b, c, 0, 0, 0)

__device__ __forceinline__ unsigned short f32_to_bf16u(float f) {
    __hip_bfloat16 hb = __float2bfloat16(f);
    return *(unsigned short*)&hb;
}
__device__ __forceinline__ float bf16u_to_f32(unsigned short u) {
    return __uint_as_float(((unsigned)u) << 16);
}

// ---------------------------------------------------------------- bucket-granularity CSR prologue
// No-memset partial-histogram design (R20). R20 lesson: the e-copy needs BLOCKS, not
// per-thread batching — 2048 blocks for the streaming copy (Guideline 11), histogram
// confined to the first 64.

__global__ __launch_bounds__(256) void btot_kernel(const int* __restrict__ dst,
                                                   int* __restrict__ part,
                                                   const float4* __restrict__ e4,
                                                   float4* __restrict__ out_e4, int n4, int E,
                                                   int NBK) {
    __shared__ int lhist[256];
    const int t = threadIdx.x;
    const int bid = blockIdx.x;
    if (bid < HIST_BLOCKS) {
        lhist[t] = 0;
        __syncthreads();
        const int chunk = (E + HIST_BLOCKS - 1) / HIST_BLOCKS;
        const int e0 = bid * chunk;
        const int e1 = min(e0 + chunk, E);
        for (int e = e0 + t; e < e1; e += 256) atomicAdd(&lhist[dst[e] >> BKT_SHIFT], 1);
        __syncthreads();
        part[bid * 256 + t] = lhist[t];  // non-atomic, every slot written
    }
    // e passthrough: simple grid-stride, coalesced
    const int stride = gridDim.x * 256;
    for (int i = bid * 256 + t; i < n4; i += stride) out_e4[i] = e4[i];
}

// single block: reduce partials -> btot; bbase = exclusive scan; seed gbcur;
// row_ptr[N]=E; q-vector prep on lanes t<64.
__global__ __launch_bounds__(256) void scan_btot_kernel(
    const int* __restrict__ part, int* __restrict__ bbase, int* __restrict__ gbcur,
    int* __restrict__ row_ptr, const float* __restrict__ We0, const float* __restrict__ ae0,
    const float* __restrict__ We1, const float* __restrict__ ae1, const float* __restrict__ We2,
    const float* __restrict__ ae2, float* __restrict__ q, int NBK, int N, int E) {
    __shared__ int sd[256];
    int t = threadIdx.x;
    int v = 0;
#pragma unroll 4
    for (int b = 0; b < HIST_BLOCKS; ++b) v += part[b * 256 + t];
    if (t >= NBK) v = 0;
    sd[t] = v;
    __syncthreads();
    for (int off = 1; off < 256; off <<= 1) {
        int tmp = (t >= off) ? sd[t - off] : 0;
        __syncthreads();
        sd[t] += tmp;
        __syncthreads();
    }
    int excl = sd[t] - v;
    if (t < NBK) {
        bbase[t] = excl;
        gbcur[t] = excl;
    }
    if (t == NBK - 1) bbase[NBK] = sd[t];
    if (t == 0) row_ptr[N] = E;
    // q prep (no barriers below — divergence safe)
    if (t < 32) {
        int k = t >> 1, hh = t & 1;
        float s = 0.f;
        for (int c = 0; c < HID; ++c) s += We0[k * 128 + hh * 64 + c] * ae0[hh * 64 + c];
        q[k * 4 + hh] = s;
    } else if (t < 48) {
        int k = t - 32;
        float s = 0.f;
        for (int c = 0; c < HID; ++c) s += We1[k * 64 + c] * ae1[c];
        q[k * 4 + 2] = s;
    } else if (t < 64) {
        int k = t - 48;
        float s = 0.f;
        for (int c = 0; c < HID; ++c) s += We2[k * 64 + c] * ae2[c];
        q[k * 4 + 3] = s;
    }
}

// ---------------------------------------------------------------- LDS-staged radix partition

__global__ __launch_bounds__(256) void partition_kernel(
    const int* __restrict__ dst, const int* __restrict__ src, const float* __restrict__ w,
    const float* __restrict__ q, int* __restrict__ gbcur, unsigned* __restrict__ part_sd,
    float4* __restrict__ part_ae4, int E, int NBK) {
    __shared__ int lhist[256];   // counts -> cursor
    __shared__ int ldelta[256];  // global_base - lds_base per bucket
    __shared__ float qs[64];
    __shared__ unsigned s_sd[PART_TMAX];
    __shared__ float4 s_ae4[PART_TMAX];
    __shared__ unsigned char s_bkt[PART_TMAX];
    const int t = threadIdx.x;
    const int e0 = blockIdx.x * PART_T;
    const int e1 = min(e0 + PART_T, E);
    const int cnt_total = e1 - e0;
    if (t < 64) qs[t] = q[t];
    lhist[t] = 0;
    __syncthreads();
    // phase 1: histogram (4x unrolled)
    for (int eb = e0 + t; eb < e1; eb += 1024) {
        int b4[4];
        bool v4[4];
#pragma unroll
        for (int j = 0; j < 4; ++j) {
            int e = eb + j * 256;
            v4[j] = e < e1;
            b4[j] = dst[v4[j] ? e : e0] >> BKT_SHIFT;
        }
#pragma unroll
        for (int j = 0; j < 4; ++j)
            if (v4[j]) atomicAdd(&lhist[b4[j]], 1);
    }
    __syncthreads();
    // phase 2: block exclusive scan of lhist -> LDS base; reserve global ranges
    int cnt = lhist[t];
    __syncthreads();
    lhist[t] = cnt;
    __syncthreads();
    for (int off = 1; off < 256; off <<= 1) {
        int tmp = (t >= off) ? lhist[t - off] : 0;
        __syncthreads();
        lhist[t] += tmp;
        __syncthreads();
    }
    int lbase = lhist[t] - cnt;  // exclusive
    int gbase = (t < NBK && cnt) ? atomicAdd(&gbcur[t], cnt) : 0;
    ldelta[t] = gbase - lbase;
    __syncthreads();
    lhist[t] = lbase;  // becomes the LDS cursor
    __syncthreads();
    // phase 3: compute logits + write records into LDS, bucket-grouped (4x unrolled)
    for (int eb = e0 + t; eb < e1; eb += 1024) {
        int d4[4], s4[4];
        bool v4[4];
        float4 a4[4];
#pragma unroll
        for (int j = 0; j < 4; ++j) {
            int e = eb + j * 256;
            v4[j] = e < e1;
            int ec = v4[j] ? e : e0;
            d4[j] = dst[ec];
            s4[j] = src[ec];
            const float4* w4p = (const float4*)(w + (size_t)ec * IN_EDGE);
            float a0 = 0.f, a1 = 0.f, a2 = 0.f, a3 = 0.f;
#pragma unroll
            for (int kq = 0; kq < 4; ++kq) {
                float4 wv = w4p[kq];
                float wk[4] = {wv.x, wv.y, wv.z, wv.w};
#pragma unroll
                for (int tt = 0; tt < 4; ++tt) {
                    int k = kq * 4 + tt;
                    a0 += wk[tt] * qs[k * 4 + 0];
                    a1 += wk[tt] * qs[k * 4 + 1];
                    a2 += wk[tt] * qs[k * 4 + 2];
                    a3 += wk[tt] * qs[k * 4 + 3];
                }
            }
            a4[j] = make_float4(a0, a1, a2, a3);
        }
#pragma unroll
        for (int j = 0; j < 4; ++j) {
            if (v4[j]) {
                int b = d4[j] >> BKT_SHIFT;
                int slot = atomicAdd(&lhist[b], 1);
                s_sd[slot] = ((unsigned)d4[j] << 16) | (unsigned)s4[j];  // both < 65536
                s_ae4[slot] = a4[j];
                s_bkt[slot] = (unsigned char)b;
            }
        }
    }
    __syncthreads();
    // phase 4: coalesced flush LDS -> global (bucket-grouped order)
    for (int r = t; r < cnt_total; r += 256) {
        int b = s_bkt[r];
        int g = ldelta[b] + r;
        part_sd[g] = s_sd[r];
        part_ae4[g] = s_ae4[r];
    }
}

// ---------------------------------------------------------------- bucket scatter + per-node CSR

__global__ __launch_bounds__(256) void bucket_scatter_kernel(
    const unsigned* __restrict__ part_sd, const float4* __restrict__ part_ae4,
    const int* __restrict__ bbase, int* __restrict__ row_ptr, unsigned short* __restrict__ csr_src,
    float2* __restrict__ ae01, float* __restrict__ ae2, float* __restrict__ ae3, int N) {
    __shared__ int cnt[256];  // per-node counts -> scan -> cursors
    const int t = threadIdx.x;
    const int node0 = blockIdx.x << BKT_SHIFT;
    const int nend = min(node0 + 256, N);
    const int p0 = bbase[blockIdx.x];
    const int p1 = bbase[blockIdx.x + 1];
    cnt[t] = 0;
    __syncthreads();
    // pass 1: per-node histogram (4x unrolled)
    for (int pb = p0 + t; pb < p1; pb += 1024) {
        int d4[4];
        bool v4[4];
#pragma unroll
        for (int j = 0; j < 4; ++j) {
            int pp = pb + j * 256;
            v4[j] = pp < p1;
            d4[j] = (int)(part_sd[v4[j] ? pp : p0] >> 16);
        }
#pragma unroll
        for (int j = 0; j < 4; ++j)
            if (v4[j]) atomicAdd(&cnt[d4[j] - node0], 1);
    }
    __syncthreads();
    // scan -> row_ptr + cursors
    int c = cnt[t];
    __syncthreads();
    cnt[t] = c;
    __syncthreads();
    for (int off = 1; off < 256; off <<= 1) {
        int tmp = (t >= off) ? cnt[t - off] : 0;
        __syncthreads();
        cnt[t] += tmp;
        __syncthreads();
    }
    int excl = cnt[t] - c;
    if (node0 + t < nend) row_ptr[node0 + t] = p0 + excl;
    __syncthreads();
    cnt[t] = p0 + excl;  // cursor
    __syncthreads();
    // pass 2: scatter records (4x unrolled)
    for (int pb = p0 + t; pb < p1; pb += 1024) {
        unsigned sd4[4];
        float4 a4[4];
        bool v4[4];
#pragma unroll
        for (int j = 0; j < 4; ++j) {
            int pp = pb + j * 256;
            v4[j] = pp < p1;
            int pc = v4[j] ? pp : p0;
            sd4[j] = part_sd[pc];  // coalesced, L2-hot
            a4[j] = part_ae4[pc];  // coalesced
        }
#pragma unroll
        for (int j = 0; j < 4; ++j) {
            if (v4[j]) {
                int d = (int)(sd4[j] >> 16);
                int slot = atomicAdd(&cnt[d - node0], 1);
                csr_src[slot] = (unsigned short)(sd4[j] & 0xffffu);
                ae01[slot] = make_float2(a4[j].x, a4[j].y);
                ae2[slot] = a4[j].z;
                ae3[slot] = a4[j].w;
            }
        }
    }
}

// ---------------------------------------------------------------- MFMA node GEMM + alpha
// A-frag: row = lane&15, k = 32*kt + 8*(lane>>4) + j.  B-frag: col = lane&15, same k.
// C/D (m89-verified): col = lane&15, row = (lane>>4)*4 + reg.
// xwb: FP8 e4m3 message payload, PERMUTED per (node,head): col' = (c&15)*4 + (c>>4).

__device__ __forceinline__ bf16x8 bfrag_w(const float* __restrict__ W, int ldc, int k0, int c) {
    bf16x8 f;
#pragma unroll
    for (int j = 0; j < 8; ++j) f[j] = (short)f32_to_bf16u(W[(k0 + j) * ldc + c]);
    return f;
}

__device__ __forceinline__ bf16x8 afrag_f32(const float* __restrict__ row, int k0) {
    float4 u = *(const float4*)(row + k0);
    float4 v = *(const float4*)(row + k0 + 4);
    bf16x8 f;
    f[0] = (short)f32_to_bf16u(u.x);
    f[1] = (short)f32_to_bf16u(u.y);
    f[2] = (short)f32_to_bf16u(u.z);
    f[3] = (short)f32_to_bf16u(u.w);
    f[4] = (short)f32_to_bf16u(v.x);
    f[5] = (short)f32_to_bf16u(v.y);
    f[6] = (short)f32_to_bf16u(v.z);
    f[7] = (short)f32_to_bf16u(v.w);
    return f;
}

template <int H, bool ABF16>
__global__ __launch_bounds__(256) void xw_alpha_mfma_kernel(
    const float* __restrict__ xf, const unsigned short* __restrict__ xb,
    const float* __restrict__ W, const float* __restrict__ a_src, const float* __restrict__ a_dst,
    unsigned char* __restrict__ xwb, float* __restrict__ alpha_src,
    float* __restrict__ alpha_dst, int ntiles) {
    const int lane = threadIdx.x & 63;
    const int wv = threadIdx.x >> 6;
    const int tile = blockIdx.x * 4 + wv;
    if (tile >= ntiles) return;
    const int cl = lane & 15, kg = lane >> 4;
    const int n0 = tile * 16;

    bf16x8 bf[2][4 * H];
    float asr[4 * H], adr[4 * H];
#pragma unroll
    for (int kt = 0; kt < 2; ++kt)
#pragma unroll
        for (int ct = 0; ct < 4 * H; ++ct)
            bf[kt][ct] = bfrag_w(W, 64 * H, kt * 32 + kg * 8, ct * 16 + cl);
#pragma unroll
    for (int ct = 0; ct < 4 * H; ++ct) {
        int hh = ct >> 2;
        int c = (ct & 3) * 16 + cl;
        asr[ct] = a_src[hh * 64 + c];
        adr[ct] = a_dst[hh * 64 + c];
    }

    bf16x8 af0, af1;
    if (ABF16) {
        const unsigned short* rp = xb + (size_t)(n0 + cl) * 64;
        af0 = *(const bf16x8*)(rp + kg * 8);
        af1 = *(const bf16x8*)(rp + 32 + kg * 8);
    } else {
        const float* rp = xf + (size_t)(n0 + cl) * 64;
        af0 = afrag_f32(rp, kg * 8);
        af1 = afrag_f32(rp, 32 + kg * 8);
    }

    f32x4 acc[4 * H];
#pragma unroll
    for (int ct = 0; ct < 4 * H; ++ct) {
        f32x4 z = {0.f, 0.f, 0.f, 0.f};
        z = MFMA16(af0, bf[0][ct], z);
        acc[ct] = MFMA16(af1, bf[1][ct], z);
    }

    // store xwb (fp8, permuted layout): node r, head hh: uint (4 fp8) at col' = cl*4
#pragma unroll
    for (int r = 0; r < 4; ++r) {
        int n = n0 + kg * 4 + r;
#pragma unroll
        for (int hh = 0; hh < H; ++hh) {
            int pk = 0;
            pk = __builtin_amdgcn_cvt_pk_fp8_f32(acc[hh * 4 + 0][r], acc[hh * 4 + 1][r], pk,
                                                 false);
            pk = __builtin_amdgcn_cvt_pk_fp8_f32(acc[hh * 4 + 2][r], acc[hh * 4 + 3][r], pk,
                                                 true);
            *(unsigned*)(xwb + ((size_t)n * H + hh) * 64 + cl * 4) = (unsigned)pk;
        }
    }

    // alpha logits: dot over the 64 cols of head hh, reduced across the 16-lane group
#pragma unroll
    for (int hh = 0; hh < H; ++hh) {
#pragma unroll
        for (int r = 0; r < 4; ++r) {
            float vs = 0.f, vd = 0.f;
#pragma unroll
            for (int q = 0; q < 4; ++q) {
                vs += acc[hh * 4 + q][r] * asr[hh * 4 + q];
                vd += acc[hh * 4 + q][r] * adr[hh * 4 + q];
            }
#pragma unroll
            for (int off = 8; off; off >>= 1) {
                vs += __shfl_xor(vs, off, 16);
                vd += __shfl_xor(vd, off, 16);
            }
            if (cl == r) {
                int n = n0 + kg * 4 + r;
                alpha_src[n * H + hh] = vs;
                alpha_dst[n * H + hh] = vd;
            }
        }
    }
}

// readout: out[n][c] = sum_k x[n][k]*Wr[k][c] + br[c], fp32 out
__global__ __launch_bounds__(256) void readout_mfma_kernel(const unsigned short* __restrict__ xb,
                                                           const float* __restrict__ Wr,
                                                           const float* __restrict__ br,
                                                           float* __restrict__ out, int ntiles) {
    const int lane = threadIdx.x & 63;
    const int wv = threadIdx.x >> 6;
    const int tile = blockIdx.x * 4 + wv;
    if (tile >= ntiles) return;
    const int cl = lane & 15, kg = lane >> 4;
    const int n0 = tile * 16;

    bf16x8 bf[2][4];
    float brv[4];
#pragma unroll
    for (int kt = 0; kt < 2; ++kt)
#pragma unroll
        for (int ct = 0; ct < 4; ++ct) bf[kt][ct] = bfrag_w(Wr, 64, kt * 32 + kg * 8, ct * 16 + cl);
#pragma unroll
    for (int ct = 0; ct < 4; ++ct) brv[ct] = br[ct * 16 + cl];

    const unsigned short* rp = xb + (size_t)(n0 + cl) * 64;
    bf16x8 af0 = *(const bf16x8*)(rp + kg * 8);
    bf16x8 af1 = *(const bf16x8*)(rp + 32 + kg * 8);

    f32x4 acc[4];
#pragma unroll
    for (int ct = 0; ct < 4; ++ct) {
        f32x4 z = {0.f, 0.f, 0.f, 0.f};
        z = MFMA16(af0, bf[0][ct], z);
        acc[ct] = MFMA16(af1, bf[1][ct], z);
    }
#pragma unroll
    for (int r = 0; r < 4; ++r) {
        int n = n0 + kg * 4 + r;
#pragma unroll
        for (int ct = 0; ct < 4; ++ct) out[(size_t)n * 64 + ct * 16 + cl] = acc[ct][r] + brv[ct];
    }
}

// ---------------------------------------------------------------- aggregation
// 16-lane-group-per-node, fp8 payload (uint per lane = 4 fp8), SoA ae planes.

template <int H, int AEOFF>
__global__ __launch_bounds__(256) void aggregate16_kernel(
    const unsigned char* __restrict__ xwb, const float* __restrict__ alpha_src,
    const float* __restrict__ alpha_dst, const void* __restrict__ aeplane,
    const int* __restrict__ row_ptr, const unsigned short* __restrict__ csr_src,
    const float* __restrict__ bias, unsigned short* __restrict__ x_out, int N) {
    const int l = threadIdx.x & 15;    // sublane within group
    const int grp = threadIdx.x >> 4;  // group within block: 0..15
    const int n = blockIdx.x * 16 + grp;
    if (n >= N) return;
    const int base = row_ptr[n];
    const int deg = row_ptr[n + 1] - base;

    float bb[4];
#pragma unroll
    for (int q = 0; q < 4; ++q) bb[q] = bias[q * 16 + l];

    float m[H], den[H], o[H][4], ad[H];
#pragma unroll
    for (int h = 0; h < H; ++h) {
        m[h] = -1e30f;
        den[h] = 0.f;
        o[h][0] = o[h][1] = o[h][2] = o[h][3] = 0.f;
        ad[h] = alpha_dst[n * H + h];
    }

    for (int start = 0; start < deg; start += 16) {
        int j = start + l;
        bool act = j < deg;
        int s = 0;
        float a[H], ev[H];
        if (act) {
            s = csr_src[base + j];
            float asv[H], aev[H];
            if (H == 2) {
                float2 ae = ((const float2*)aeplane)[base + j];
                aev[0] = ae.x;
                aev[H - 1] = ae.y;
                float2 as2 = *((const float2*)alpha_src + s);
                asv[0] = as2.x;
                asv[H - 1] = as2.y;
            } else {
                aev[0] = ((const float*)aeplane)[base + j];
                asv[0] = alpha_src[s];
            }
#pragma unroll
            for (int h = 0; h < H; ++h) {
                float av = asv[h] + ad[h] + aev[h];
                a[h] = (av > 0.f) ? av : 0.2f * av;
            }
        } else {
#pragma unroll
            for (int h = 0; h < H; ++h) a[h] = -1e30f;
        }
        int cnt = min(deg - start, 16);
#pragma unroll
        for (int h = 0; h < H; ++h) {
            float cm = a[h];
#pragma unroll
            for (int off = 8; off; off >>= 1) cm = fmaxf(cm, __shfl_xor(cm, off, 16));
            float m_new = fmaxf(m[h], cm);
            float scale = __expf(m[h] - m_new);
            ev[h] = act ? __expf(a[h] - m_new) : 0.f;
            float cs = ev[h];
#pragma unroll
            for (int off = 8; off; off >>= 1) cs += __shfl_xor(cs, off, 16);
            den[h] = den[h] * scale + cs;
#pragma unroll
            for (int q = 0; q < 4; ++q) o[h][q] *= scale;
            m[h] = m_new;
        }
#pragma unroll 8
        for (int jj = 0; jj < cnt; ++jj) {
            int sj = __shfl(s, jj, 16);
#pragma unroll
            for (int h = 0; h < H; ++h) {
                float ej = __shfl(ev[h], jj, 16);
                unsigned v = *((const unsigned*)(xwb + ((size_t)sj * H + h) * 64) + l);
                f32x2 lo = __builtin_amdgcn_cvt_pk_f32_fp8((int)v, false);
                f32x2 hi = __builtin_amdgcn_cvt_pk_f32_fp8((int)v, true);
                o[h][0] += ej * lo[0];
                o[h][1] += ej * lo[1];
                o[h][2] += ej * hi[0];
                o[h][3] += ej * hi[1];
            }
        }
    }

#pragma unroll
    for (int q = 0; q < 4; ++q) {
        float acc = 0.f;
#pragma unroll
        for (int h = 0; h < H; ++h) acc += o[h][q] / (den[h] + 1e-16f);
        float r = acc * (H == 2 ? 0.5f : 1.f) + bb[q];
        r = r / (1.f + __expf(-r));  // silu
        x_out[(size_t)n * 64 + q * 16 + l] = f32_to_bf16u(r);  // un-permute: col = q*16+l
    }
}

// ---------------------------------------------------------------- launcher

static inline char* carve(char*& p, size_t bytes) {
    char* r = p;
    p += (bytes + 255) & ~(size_t)255;
    return r;
}

extern "C" void kernel_launch(void* const* d_in, const int* in_sizes, int n_in, void* d_out,
                              int out_size, void* d_ws, size_t ws_size, hipStream_t stream) {
    const int N = in_sizes[0] / IN_NODE;
    const int E = in_sizes[1] / IN_EDGE;

    const float* h = (const float*)d_in[0];
    const float* e = (const float*)d_in[1];
    const int* edge_index = (const int*)d_in[2];
    const float* w = (const float*)d_in[3];
    const float* W0 = (const float*)d_in[4];
    const float* as0 = (const float*)d_in[5];
    const float* ad0 = (const float*)d_in[6];
    const float* We0 = (const float*)d_in[7];
    const float* ae0 = (const float*)d_in[8];
    const float* b0 = (const float*)d_in[9];
    const float* W1 = (const float*)d_in[10];
    const float* as1 = (const float*)d_in[11];
    const float* ad1 = (const float*)d_in[12];
    const float* We1 = (const float*)d_in[13];
    const float* ae1 = (const float*)d_in[14];
    const float* b1 = (const float*)d_in[15];
    const float* W2 = (const float*)d_in[16];
    const float* as2 = (const float*)d_in[17];
    const float* ad2 = (const float*)d_in[18];
    const float* We2 = (const float*)d_in[19];
    const float* ae2 = (const float*)d_in[20];
    const float* b2 = (const float*)d_in[21];
    const float* Wr = (const float*)d_in[22];
    const float* br = (const float*)d_in[23];

    const int* src = edge_index;
    const int* dst = edge_index + E;

    float* out_x = (float*)d_out;                        // [N,64]
    float* out_e = (float*)d_out + (size_t)N * IN_NODE;  // [E,16] passthrough

    char* p = (char*)d_ws;
    unsigned char* xwb = (unsigned char*)carve(p, (size_t)N * 128);      // fp8 [N,H,64] perm
    unsigned short* xA = (unsigned short*)carve(p, (size_t)N * 64 * 2);  // bf16 [N,64]
    unsigned short* xB = (unsigned short*)carve(p, (size_t)N * 64 * 2);  // bf16 [N,64]
    float* csr_ae01 = (float*)carve(p, (size_t)E * 2 * 4);  // SoA logit planes
    float* csr_ae2 = (float*)carve(p, (size_t)E * 4);
    float* csr_ae3 = (float*)carve(p, (size_t)E * 4);
    float* a_src = (float*)carve(p, (size_t)N * 2 * 4);
    float* a_dst = (float*)carve(p, (size_t)N * 2 * 4);
    float* qall = (float*)carve(p, 64 * 4);
    int* row_ptr = (int*)carve(p, (size_t)(N + 1) * 4);
    int* hist_part = (int*)carve(p, HIST_BLOCKS * 256 * 4);  // no-init partials
    int* bbase = (int*)carve(p, 257 * 4);
    unsigned short* csr_src = (unsigned short*)carve(p, (size_t)E * 2);
    unsigned* part_sd = (unsigned*)carve(p, (size_t)E * 4);
    float* part_ae4 = (float*)carve(p, (size_t)E * 4 * 4);
    int* gbcur = (int*)carve(p, 1024 * 4);

    const int ngrid16 = (N + 15) / 16;
    const int NBK = (N + 255) >> BKT_SHIFT;             // dst-node buckets of 256
    const int PART_BLOCKS = (E + PART_T - 1) / PART_T;  // 512 blocks @ PART_T=1563
    const int ntiles = (N + 15) / 16;                   // 16-node MFMA tiles
    const int ggrid = (ntiles + 3) / 4;                 // 4 waves/block, 1 tile/wave
    const int n4 = E * IN_EDGE / 4;                     // e passthrough float4 count

    // bucket-granularity CSR prologue (no memset; partial-hist accumulation);
    // e-copy rides in btot — 2048 blocks for streaming BW (Guideline 11)
    btot_kernel<<<2048, 256, 0, stream>>>(dst, hist_part, (const float4*)e, (float4*)out_e, n4, E,
                                          NBK);
    scan_btot_kernel<<<1, 256, 0, stream>>>(hist_part, bbase, gbcur, row_ptr, We0, ae0, We1, ae1,
                                            We2, ae2, qall, NBK, N, E);

    // LDS-staged partition (logits fused) + bucket scatter (builds row_ptr)
    partition_kernel<<<PART_BLOCKS, 256, 0, stream>>>(dst, src, w, qall, gbcur, part_sd,
                                                      (float4*)part_ae4, E, NBK);
    bucket_scatter_kernel<<<NBK, 256, 0, stream>>>(part_sd, (const float4*)part_ae4, bbase,
                                                   row_ptr, csr_src, (float2*)csr_ae01, csr_ae2,
                                                   csr_ae3, N);

    // layer 0 (H=2), input h fp32
    xw_alpha_mfma_kernel<2, false><<<ggrid, 256, 0, stream>>>(h, nullptr, W0, as0, ad0, xwb, a_src,
                                                              a_dst, ntiles);
    aggregate16_kernel<2, 0><<<ngrid16, 256, 0, stream>>>(xwb, a_src, a_dst, csr_ae01, row_ptr,
                                                          csr_src, b0, xA, N);
    // layer 1 (H=1), input xA bf16
    xw_alpha_mfma_kernel<1, true><<<ggrid, 256, 0, stream>>>(nullptr, xA, W1, as1, ad1, xwb, a_src,
                                                             a_dst, ntiles);
    aggregate16_kernel<1, 2><<<ngrid16, 256, 0, stream>>>(xwb, a_src, a_dst, csr_ae2, row_ptr,
                                                          csr_src, b1, xB, N);
    // layer 2 (H=1), input xB bf16
    xw_alpha_mfma_kernel<1, true><<<ggrid, 256, 0, stream>>>(nullptr, xB, W2, as2, ad2, xwb, a_src,
                                                             a_dst, ntiles);
    aggregate16_kernel<1, 3><<<ngrid16, 256, 0, stream>>>(xwb, a_src, a_dst, csr_ae3, row_ptr,
                                                          csr_src, b2, xA, N);
    // readout, input xA bf16
    readout_mfma_kernel<<<ggrid, 256, 0, stream>>>(xA, Wr, br, out_x, ntiles);
}